// Round 5
// baseline (536.446 us; speedup 1.0000x reference)
//
#include <hip/hip_runtime.h>
#include <hip/hip_bf16.h>
#include <math.h>

constexpr int Bn  = 2;
constexpr int Tn  = 2048;
constexpr int NHn = 16;
constexpr int NKVn= 8;
constexpr int Gn  = 512;
constexpr int TKn = 64;

typedef __attribute__((ext_vector_type(8))) __bf16 bf16x8;
typedef __attribute__((ext_vector_type(4))) __bf16 bf16x4;
typedef __attribute__((ext_vector_type(2))) __bf16 bf16x2;
typedef __attribute__((ext_vector_type(4))) float f32x4;

__device__ __forceinline__ void gload_lds16(const void* g, void* l) {
  __builtin_amdgcn_global_load_lds(
      (const __attribute__((address_space(1))) unsigned int*)g,
      (__attribute__((address_space(3))) unsigned int*)l, 16, 0, 0);
}

// ---------------------------------------------------------------------------
// gemm_kvqa_8ph (R20): 256x256 tile, 8 waves, BK=64 (2 sub-phases of 32),
// 4 phases per K-tile with counted vmcnt(4) (never 0 in steady state),
// double-buffered 128 KiB LDS, proven c4^((r>>1)&3) swizzle (0 conflicts).
// ---------------------------------------------------------------------------
__global__ __launch_bounds__(512) void gemm_kvqa_8ph(
    const __bf16* __restrict__ A, const __bf16* __restrict__ Bt,
    float* __restrict__ Cf, __bf16* __restrict__ Cq)
{
  constexpr int K = 2048;
  constexpr int NT = K / 64;                  // 32 K-tiles
  __shared__ __bf16 lds[2][2][2][256][32];    // [buf][op A/B][ph][row][col] = 128 KiB
  const int tid = threadIdx.x;
  const int wid = tid >> 6, lane = tid & 63;
  const int wm = wid >> 2, wn = wid & 3;      // 2 (M) x 4 (N) wave grid
  const int row0 = blockIdx.y * 256, col0 = blockIdx.x * 256;

  f32x4 acc[8][4];
  const f32x4 zero = {0.f, 0.f, 0.f, 0.f};
  #pragma unroll
  for (int i = 0; i < 8; ++i)
    #pragma unroll
    for (int j = 0; j < 4; ++j) acc[i][j] = zero;

  // stage one (op, ph) half-tile (256 rows x 32 cols) of K-tile kt into buf
  auto stage1 = [&](int kt, int op, int ph, int buf) {
    long k0 = (long)kt * 64 + ph * 32;
    const __bf16* src = op ? Bt : A;
    const int base0 = op ? col0 : row0;
    #pragma unroll
    for (int l = 0; l < 2; ++l) {
      int u = l * 512 + tid;
      int r = u >> 2, c4 = u & 3;
      long csrc = (long)((c4 ^ ((r >> 1) & 3)) * 8);
      gload_lds16(src + (long)(base0 + r) * K + k0 + csrc, &lds[buf][op][ph][r][c4 * 8]);
    }
  };

  // prologue: stage kt0 halves H0..H3 = (A,0),(B,0),(A,1),(B,1)
  stage1(0, 0, 0, 0);
  stage1(0, 1, 0, 0);
  stage1(0, 0, 1, 0);
  stage1(0, 1, 1, 0);
  asm volatile("s_waitcnt vmcnt(4)" ::: "memory");   // H0,H1 done; H2,H3 in flight
  asm volatile("s_barrier" ::: "memory");

  for (int kt = 0; kt < NT; ++kt) {
    const int buf = kt & 1;
    const bool pre = (kt + 1 < NT);
    bf16x8 afA[4], afB[4], bf[4];

    // ---- P0: ph0, acc rows mf0-3 ----
    #pragma unroll
    for (int i = 0; i < 4; ++i) {
      int r = wm * 128 + i * 16 + (lane & 15);
      int c4 = (lane >> 4) ^ ((r >> 1) & 3);
      afA[i] = *(const bf16x8*)&lds[buf][0][0][r][c4 * 8];
    }
    #pragma unroll
    for (int i = 0; i < 4; ++i) {
      int r = wn * 64 + i * 16 + (lane & 15);
      int c4 = (lane >> 4) ^ ((r >> 1) & 3);
      bf[i] = *(const bf16x8*)&lds[buf][1][0][r][c4 * 8];
    }
    if (pre) stage1(kt + 1, 0, 0, buf ^ 1);
    asm volatile("s_barrier" ::: "memory");
    asm volatile("s_waitcnt lgkmcnt(0)" ::: "memory");
    __builtin_amdgcn_sched_barrier(0);
    __builtin_amdgcn_s_setprio(1);
    #pragma unroll
    for (int i = 0; i < 4; ++i)
      #pragma unroll
      for (int j = 0; j < 4; ++j)
        acc[i][j] = __builtin_amdgcn_mfma_f32_16x16x32_bf16(afA[i], bf[j], acc[i][j], 0, 0, 0);
    __builtin_amdgcn_s_setprio(0);
    asm volatile("s_barrier" ::: "memory");

    // ---- P1: ph0, acc rows mf4-7 ----
    #pragma unroll
    for (int i = 0; i < 4; ++i) {
      int r = wm * 128 + (i + 4) * 16 + (lane & 15);
      int c4 = (lane >> 4) ^ ((r >> 1) & 3);
      afB[i] = *(const bf16x8*)&lds[buf][0][0][r][c4 * 8];
    }
    if (pre) {
      stage1(kt + 1, 1, 0, buf ^ 1);
      asm volatile("s_waitcnt vmcnt(4)" ::: "memory");  // confirm kt.H2,H3
    } else {
      asm volatile("s_waitcnt vmcnt(0)" ::: "memory");
    }
    asm volatile("s_barrier" ::: "memory");
    asm volatile("s_waitcnt lgkmcnt(0)" ::: "memory");
    __builtin_amdgcn_sched_barrier(0);
    __builtin_amdgcn_s_setprio(1);
    #pragma unroll
    for (int i = 0; i < 4; ++i)
      #pragma unroll
      for (int j = 0; j < 4; ++j)
        acc[i + 4][j] = __builtin_amdgcn_mfma_f32_16x16x32_bf16(afB[i], bf[j], acc[i + 4][j], 0, 0, 0);
    __builtin_amdgcn_s_setprio(0);
    asm volatile("s_barrier" ::: "memory");

    // ---- P2: ph1, acc rows mf0-3 ----
    #pragma unroll
    for (int i = 0; i < 4; ++i) {
      int r = wm * 128 + i * 16 + (lane & 15);
      int c4 = (lane >> 4) ^ ((r >> 1) & 3);
      afA[i] = *(const bf16x8*)&lds[buf][0][1][r][c4 * 8];
    }
    #pragma unroll
    for (int i = 0; i < 4; ++i) {
      int r = wn * 64 + i * 16 + (lane & 15);
      int c4 = (lane >> 4) ^ ((r >> 1) & 3);
      bf[i] = *(const bf16x8*)&lds[buf][1][1][r][c4 * 8];
    }
    if (pre) stage1(kt + 1, 0, 1, buf ^ 1);
    asm volatile("s_barrier" ::: "memory");
    asm volatile("s_waitcnt lgkmcnt(0)" ::: "memory");
    __builtin_amdgcn_sched_barrier(0);
    __builtin_amdgcn_s_setprio(1);
    #pragma unroll
    for (int i = 0; i < 4; ++i)
      #pragma unroll
      for (int j = 0; j < 4; ++j)
        acc[i][j] = __builtin_amdgcn_mfma_f32_16x16x32_bf16(afA[i], bf[j], acc[i][j], 0, 0, 0);
    __builtin_amdgcn_s_setprio(0);
    asm volatile("s_barrier" ::: "memory");

    // ---- P3: ph1, acc rows mf4-7 ----
    #pragma unroll
    for (int i = 0; i < 4; ++i) {
      int r = wm * 128 + (i + 4) * 16 + (lane & 15);
      int c4 = (lane >> 4) ^ ((r >> 1) & 3);
      afB[i] = *(const bf16x8*)&lds[buf][0][1][r][c4 * 8];
    }
    if (pre) {
      stage1(kt + 1, 1, 1, buf ^ 1);
      asm volatile("s_waitcnt vmcnt(4)" ::: "memory");  // confirm kt+1.H0,H1
    }
    asm volatile("s_barrier" ::: "memory");
    asm volatile("s_waitcnt lgkmcnt(0)" ::: "memory");
    __builtin_amdgcn_sched_barrier(0);
    __builtin_amdgcn_s_setprio(1);
    #pragma unroll
    for (int i = 0; i < 4; ++i)
      #pragma unroll
      for (int j = 0; j < 4; ++j)
        acc[i + 4][j] = __builtin_amdgcn_mfma_f32_16x16x32_bf16(afB[i], bf[j], acc[i + 4][j], 0, 0, 0);
    __builtin_amdgcn_s_setprio(0);
    asm volatile("s_barrier" ::: "memory");
  }

  const int crow = (lane >> 4) * 4, ccol = lane & 15;
  const bool isQ = (col0 >= 3072);
  #pragma unroll
  for (int mf = 0; mf < 8; ++mf)
    #pragma unroll
    for (int nf = 0; nf < 4; ++nf)
      #pragma unroll
      for (int j = 0; j < 4; ++j) {
        long r = row0 + wm * 128 + mf * 16 + crow + j;
        long c = col0 + wn * 64 + nf * 16 + ccol;
        float v = acc[mf][nf][j];
        if (isQ) Cq[r * 1024 + (c - 3072)] = (__bf16)v;
        else     Cf[r * 3072 + c] = v;
      }
}

// ---------------------------------------------------------------------------
// gemm_split_2b (R23): 3-product split GEMM, 128x192 tile, 4 waves (2Mx2N,
// 64x96/wave, acc[4][6]), BK=32, 3 uniform phases (24 MFMA each).
// LDS [Ah|Al|Bh|Bl] = 40 KiB/buf, dbuf = 80 KiB -> EXACTLY 2 blocks/CU:
// block A's ds_read/staging phases overlap block B's MFMA phases.
// Grid 16x32 = 512 blocks = 2/CU, no tail.
// Counted vmcnt: pieces SB(6)=Bh+Bl, SAh(2), SAl(2). P0 issues SB+SAh
// (outstanding 10); P1 waits vmcnt(8) (drains SAl(kt)); P2 issues SAl,
// waits vmcnt(2) (drains SB+SAh(kt+1), leaves SAl in flight). Never 0.
// Per-acc product order hh->hl->lh per K-slice == R19/R22 (bit-identical).
// ---------------------------------------------------------------------------
__global__ __launch_bounds__(256) void gemm_split_2b(
    const __bf16* __restrict__ Ah, const __bf16* __restrict__ Al,
    const __bf16* __restrict__ Bh, const __bf16* __restrict__ Bl,
    float* __restrict__ C, int M, int N, int K, float alpha)
{
  const int NT = K >> 5;                      // BK = 32
  constexpr int LA_H = 0;                     // 128*32 = 4096
  constexpr int LA_L = 4096;
  constexpr int LB_H = 8192;                  // 192*32 = 6144
  constexpr int LB_L = 14336;
  constexpr int LBUF = 20480;                 // elems per buffer
  __shared__ __bf16 sm[2 * LBUF];             // 81920 B = 80 KiB
  const int tid = threadIdx.x;
  const int wid = tid >> 6, lane = tid & 63;
  const int wm = wid >> 1, wn = wid & 1;      // 2 (M) x 2 (N)
  const int row0 = blockIdx.y * 128, col0 = blockIdx.x * 192;

  f32x4 acc[4][6];
  const f32x4 zero = {0.f, 0.f, 0.f, 0.f};
  #pragma unroll
  for (int i = 0; i < 4; ++i)
    #pragma unroll
    for (int j = 0; j < 6; ++j) acc[i][j] = zero;

  // A half-tile (128x32), stream which (0=hi,1=lo): 2 loads/thread
  auto stageA = [&](int kt, int buf, int which) {
    long k0 = (long)kt * 32;
    const __bf16* src = which ? Al : Ah;
    __bf16* dst = &sm[buf * LBUF + (which ? LA_L : LA_H)];
    #pragma unroll
    for (int l = 0; l < 2; ++l) {
      int u = l * 256 + tid;
      int r = u >> 2, c4 = u & 3;
      long csrc = (long)((c4 ^ ((r >> 1) & 3)) * 8);
      gload_lds16(src + (long)(row0 + r) * K + k0 + csrc, dst + u * 8);
    }
  };
  // B half-tile (192x32), stream which (0=hi,1=lo): 3 loads/thread
  auto stageB = [&](int kt, int buf, int which) {
    long k0 = (long)kt * 32;
    const __bf16* src = which ? Bl : Bh;
    __bf16* dst = &sm[buf * LBUF + (which ? LB_L : LB_H)];
    #pragma unroll
    for (int l = 0; l < 3; ++l) {
      int u = l * 256 + tid;
      int r = u >> 2, c4 = u & 3;
      long csrc = (long)((c4 ^ ((r >> 1) & 3)) * 8);
      gload_lds16(src + (long)(col0 + r) * K + k0 + csrc, dst + u * 8);
    }
  };

  // prologue: SB(0)[6], SAh(0)[2], SAl(0)[2]; confirm SB+SAh, SAl in flight
  stageB(0, 0, 0);
  stageB(0, 0, 1);
  stageA(0, 0, 0);
  stageA(0, 0, 1);
  asm volatile("s_waitcnt vmcnt(2)" ::: "memory");
  asm volatile("s_barrier" ::: "memory");

  for (int kt = 0; kt < NT; ++kt) {
    const int buf = kt & 1;
    const bool pre = (kt + 1 < NT);
    bf16x8 a_h[4], a_l[4], b_h[6], b_l[6];

    // ---- P0: hh (24 MFMA) ----
    #pragma unroll
    for (int i = 0; i < 4; ++i) {
      int r = wm * 64 + i * 16 + (lane & 15);
      int c4 = (lane >> 4) ^ ((r >> 1) & 3);
      a_h[i] = *(const bf16x8*)&sm[buf * LBUF + LA_H + r * 32 + c4 * 8];
    }
    #pragma unroll
    for (int j = 0; j < 6; ++j) {
      int r = wn * 96 + j * 16 + (lane & 15);
      int c4 = (lane >> 4) ^ ((r >> 1) & 3);
      b_h[j] = *(const bf16x8*)&sm[buf * LBUF + LB_H + r * 32 + c4 * 8];
    }
    if (pre) {
      stageB(kt + 1, buf ^ 1, 0);       // 3 loads
      stageB(kt + 1, buf ^ 1, 1);       // 3 loads
      stageA(kt + 1, buf ^ 1, 0);       // 2 loads (SAh)
    }
    asm volatile("s_barrier" ::: "memory");
    asm volatile("s_waitcnt lgkmcnt(0)" ::: "memory");
    __builtin_amdgcn_sched_barrier(0);
    __builtin_amdgcn_s_setprio(1);
    #pragma unroll
    for (int i = 0; i < 4; ++i)
      #pragma unroll
      for (int j = 0; j < 6; ++j)
        acc[i][j] = __builtin_amdgcn_mfma_f32_16x16x32_bf16(a_h[i], b_h[j], acc[i][j], 0, 0, 0);
    __builtin_amdgcn_s_setprio(0);
    asm volatile("s_barrier" ::: "memory");

    // ---- P1: hl (24 MFMA) ----
    #pragma unroll
    for (int j = 0; j < 6; ++j) {
      int r = wn * 96 + j * 16 + (lane & 15);
      int c4 = (lane >> 4) ^ ((r >> 1) & 3);
      b_l[j] = *(const bf16x8*)&sm[buf * LBUF + LB_L + r * 32 + c4 * 8];
    }
    if (pre)
      asm volatile("s_waitcnt vmcnt(8)" ::: "memory");  // confirm SAl(kt)
    else
      asm volatile("s_waitcnt vmcnt(0)" ::: "memory");
    asm volatile("s_barrier" ::: "memory");
    asm volatile("s_waitcnt lgkmcnt(0)" ::: "memory");
    __builtin_amdgcn_sched_barrier(0);
    __builtin_amdgcn_s_setprio(1);
    #pragma unroll
    for (int i = 0; i < 4; ++i)
      #pragma unroll
      for (int j = 0; j < 6; ++j)
        acc[i][j] = __builtin_amdgcn_mfma_f32_16x16x32_bf16(a_h[i], b_l[j], acc[i][j], 0, 0, 0);
    __builtin_amdgcn_s_setprio(0);
    asm volatile("s_barrier" ::: "memory");

    // ---- P2: lh (24 MFMA) ----
    #pragma unroll
    for (int i = 0; i < 4; ++i) {
      int r = wm * 64 + i * 16 + (lane & 15);
      int c4 = (lane >> 4) ^ ((r >> 1) & 3);
      a_l[i] = *(const bf16x8*)&sm[buf * LBUF + LA_L + r * 32 + c4 * 8];
    }
    if (pre) {
      stageA(kt + 1, buf ^ 1, 1);       // 2 loads (SAl)
      asm volatile("s_waitcnt vmcnt(2)" ::: "memory");  // confirm SB+SAh(kt+1)
    }
    asm volatile("s_barrier" ::: "memory");
    asm volatile("s_waitcnt lgkmcnt(0)" ::: "memory");
    __builtin_amdgcn_sched_barrier(0);
    __builtin_amdgcn_s_setprio(1);
    #pragma unroll
    for (int i = 0; i < 4; ++i)
      #pragma unroll
      for (int j = 0; j < 6; ++j)
        acc[i][j] = __builtin_amdgcn_mfma_f32_16x16x32_bf16(a_l[i], b_h[j], acc[i][j], 0, 0, 0);
    __builtin_amdgcn_s_setprio(0);
    asm volatile("s_barrier" ::: "memory");
  }

  const int crow = (lane >> 4) * 4, ccol = lane & 15;
  #pragma unroll
  for (int mf = 0; mf < 4; ++mf)
    #pragma unroll
    for (int nf = 0; nf < 6; ++nf)
      #pragma unroll
      for (int j = 0; j < 4; ++j) {
        long r = row0 + wm * 64 + mf * 16 + crow + j;
        long c = col0 + wn * 96 + nf * 16 + ccol;
        C[r * N + c] = acc[mf][nf][j] * alpha;
      }
}

// ---------------------------------------------------------------------------
// Unified pipelined GEMM (R13 schedule, runtime K): C = A @ Bt^T.
// EPI 0: bf16 out.  EPI 1: rope bf16 q layout (N=2048).  EPI 2: f32 * rs[r].
// ---------------------------------------------------------------------------
template<int EPI>
__global__ __launch_bounds__(256) void gemm_pipe(
    const __bf16* __restrict__ A, const __bf16* __restrict__ Bt,
    void* __restrict__ Cp, int N, int K,
    const float* __restrict__ cosb, const float* __restrict__ sinb,
    const float* __restrict__ rs)
{
  const int NT = K >> 6;
  __shared__ __bf16 lds[2][2][2][128][32];
  const int tid = threadIdx.x;
  const int wid = tid >> 6, lane = tid & 63;
  const int wm = wid >> 1, wn = wid & 1;
  const int row0 = blockIdx.y * 128, col0 = blockIdx.x * 128;

  f32x4 acc[4][4];
  const f32x4 zero = {0.f, 0.f, 0.f, 0.f};
  #pragma unroll
  for (int i = 0; i < 4; ++i)
    #pragma unroll
    for (int j = 0; j < 4; ++j) acc[i][j] = zero;

  auto stage = [&](int kt, int p, int buf) {
    long k0 = (long)kt * 64 + p * 32;
    #pragma unroll
    for (int l = 0; l < 2; ++l) {
      int u = l * 256 + tid;
      int r = u >> 2, c4 = u & 3;
      long csrc = (long)((c4 ^ ((r >> 1) & 3)) * 8);
      gload_lds16(A  + (long)(row0 + r) * K + k0 + csrc, &lds[buf][0][p][r][c4 * 8]);
      gload_lds16(Bt + (long)(col0 + r) * K + k0 + csrc, &lds[buf][1][p][r][c4 * 8]);
    }
  };

  stage(0, 0, 0);
  stage(0, 1, 0);

  for (int kt = 0; kt < NT; ++kt) {
    const int buf = kt & 1;
    #pragma unroll
    for (int ph = 0; ph < 2; ++ph) {
      if (kt + 1 < NT) {
        stage(kt + 1, ph, buf ^ 1);
        asm volatile("s_waitcnt vmcnt(8)" ::: "memory");
      } else {
        if (ph == 0) asm volatile("s_waitcnt vmcnt(4)" ::: "memory");
        else         asm volatile("s_waitcnt vmcnt(0)" ::: "memory");
      }
      asm volatile("s_barrier" ::: "memory");
      bf16x8 af[4], bfr[4];
      #pragma unroll
      for (int mf = 0; mf < 4; ++mf) {
        int r = wm * 64 + mf * 16 + (lane & 15);
        int c4 = (lane >> 4) ^ ((r >> 1) & 3);
        af[mf] = *(const bf16x8*)&lds[buf][0][ph][r][c4 * 8];
      }
      #pragma unroll
      for (int nf = 0; nf < 4; ++nf) {
        int r = wn * 64 + nf * 16 + (lane & 15);
        int c4 = (lane >> 4) ^ ((r >> 1) & 3);
        bfr[nf] = *(const bf16x8*)&lds[buf][1][ph][r][c4 * 8];
      }
      __builtin_amdgcn_s_setprio(1);
      #pragma unroll
      for (int mf = 0; mf < 4; ++mf)
        #pragma unroll
        for (int nf = 0; nf < 4; ++nf)
          acc[mf][nf] = __builtin_amdgcn_mfma_f32_16x16x32_bf16(af[mf], bfr[nf], acc[mf][nf], 0, 0, 0);
      __builtin_amdgcn_s_setprio(0);
      asm volatile("s_barrier" ::: "memory");
    }
  }

  const int crow = (lane >> 4) * 4, ccol = lane & 15;
  if constexpr (EPI == 1) {
    __bf16* C = (__bf16*)Cp;
    if (wn == 1) {
      #pragma unroll
      for (int mf = 0; mf < 4; ++mf)
        #pragma unroll
        for (int j = 0; j < 4; ++j) {
          long r = row0 + wm * 64 + mf * 16 + crow + j;
          int t = (int)(r & 2047);
          #pragma unroll
          for (int nfp = 0; nfp < 2; ++nfp) {
            int jj = nfp * 16 + ccol;
            float c = cosb[t * 64 + jj], s = sinb[t * 64 + jj];
            float x1 = acc[mf][nfp][j];
            float x2 = acc[mf][nfp + 2][j];
            C[r * N + col0 + 64 + jj] = (__bf16)(x1 * c + x2 * s);
            C[r * N + col0 + 96 + jj] = (__bf16)(-x1 * s + x2 * c);
          }
        }
    } else {
      #pragma unroll
      for (int mf = 0; mf < 4; ++mf)
        #pragma unroll
        for (int nf = 0; nf < 4; ++nf)
          #pragma unroll
          for (int j = 0; j < 4; ++j) {
            long r = row0 + wm * 64 + mf * 16 + crow + j;
            long c = col0 + nf * 16 + ccol;
            C[r * N + c] = (__bf16)acc[mf][nf][j];
          }
    }
  } else {
    #pragma unroll
    for (int mf = 0; mf < 4; ++mf)
      #pragma unroll
      for (int nf = 0; nf < 4; ++nf)
        #pragma unroll
        for (int j = 0; j < 4; ++j) {
          long r = row0 + wm * 64 + mf * 16 + crow + j;
          long c = col0 + wn * 64 + nf * 16 + ccol;
          float v = acc[mf][nf][j];
          if constexpr (EPI == 2)
            ((float*)Cp)[r * N + c] = v * rs[r];
          else
            ((__bf16*)Cp)[r * N + c] = (__bf16)v;
        }
  }
}

// ---------------------------------------------------------------------------
// Split-precision GEMM, R19 (kept for the small selection GEMM).
// ---------------------------------------------------------------------------
__global__ __launch_bounds__(256) void gemm_split(
    const __bf16* __restrict__ Ah, const __bf16* __restrict__ Al,
    const __bf16* __restrict__ Bh, const __bf16* __restrict__ Bl,
    float* __restrict__ C, int M, int N, int K, float alpha,
    long sA, long sB, long sC)
{
  const int NT = K >> 5;                       // BK = 32
  __shared__ __bf16 lds[2][4][128][32];        // [buf][Ah|Al|Bh|Bl][row][col]
  const int tid = threadIdx.x;
  const int wid = tid >> 6, lane = tid & 63;
  const int wm = wid >> 1, wn = wid & 1;
  const int row0 = blockIdx.y * 128, col0 = blockIdx.x * 128;
  Ah += (long)blockIdx.z * sA;  Al += (long)blockIdx.z * sA;
  Bh += (long)blockIdx.z * sB;  Bl += (long)blockIdx.z * sB;

  f32x4 acc[4][4];
  const f32x4 zero = {0.f, 0.f, 0.f, 0.f};
  #pragma unroll
  for (int i = 0; i < 4; ++i)
    #pragma unroll
    for (int j = 0; j < 4; ++j) acc[i][j] = zero;

  auto stage = [&](int kt, int buf) {
    long k0 = (long)kt * 32;
    #pragma unroll
    for (int l = 0; l < 2; ++l) {
      int u = l * 256 + tid;
      int r = u >> 2, c4 = u & 3;
      long csrc = (long)((c4 ^ ((r >> 1) & 3)) * 8);
      long ga = (long)(row0 + r) * K + k0 + csrc;
      long gb = (long)(col0 + r) * K + k0 + csrc;
      gload_lds16(Ah + ga, &lds[buf][0][r][c4 * 8]);
      gload_lds16(Al + ga, &lds[buf][1][r][c4 * 8]);
      gload_lds16(Bh + gb, &lds[buf][2][r][c4 * 8]);
      gload_lds16(Bl + gb, &lds[buf][3][r][c4 * 8]);
    }
  };

  stage(0, 0);

  for (int kt = 0; kt < NT; ++kt) {
    const int buf = kt & 1;
    if (kt + 1 < NT) {
      stage(kt + 1, buf ^ 1);
      asm volatile("s_waitcnt vmcnt(8)" ::: "memory");
    } else {
      asm volatile("s_waitcnt vmcnt(0)" ::: "memory");
    }
    asm volatile("s_barrier" ::: "memory");
    bf16x8 ah[4], al[4], bh[4], bl[4];
    #pragma unroll
    for (int mf = 0; mf < 4; ++mf) {
      int r = wm * 64 + mf * 16 + (lane & 15);
      int c4 = (lane >> 4) ^ ((r >> 1) & 3);
      ah[mf] = *(const bf16x8*)&lds[buf][0][r][c4 * 8];
      al[mf] = *(const bf16x8*)&lds[buf][1][r][c4 * 8];
    }
    #pragma unroll
    for (int nf = 0; nf < 4; ++nf) {
      int r = wn * 64 + nf * 16 + (lane & 15);
      int c4 = (lane >> 4) ^ ((r >> 1) & 3);
      bh[nf] = *(const bf16x8*)&lds[buf][2][r][c4 * 8];
      bl[nf] = *(const bf16x8*)&lds[buf][3][r][c4 * 8];
    }
    __builtin_amdgcn_s_setprio(1);
    #pragma unroll
    for (int mf = 0; mf < 4; ++mf)
      #pragma unroll
      for (int nf = 0; nf < 4; ++nf) {
        acc[mf][nf] = __builtin_amdgcn_mfma_f32_16x16x32_bf16(ah[mf], bh[nf], acc[mf][nf], 0, 0, 0);
        acc[mf][nf] = __builtin_amdgcn_mfma_f32_16x16x32_bf16(ah[mf], bl[nf], acc[mf][nf], 0, 0, 0);
        acc[mf][nf] = __builtin_amdgcn_mfma_f32_16x16x32_bf16(al[mf], bh[nf], acc[mf][nf], 0, 0, 0);
      }
    __builtin_amdgcn_s_setprio(0);
    asm volatile("s_barrier" ::: "memory");
  }

  const int crow = (lane >> 4) * 4, ccol = lane & 15;
  #pragma unroll
  for (int mf = 0; mf < 4; ++mf)
    #pragma unroll
    for (int nf = 0; nf < 4; ++nf)
      #pragma unroll
      for (int j = 0; j < 4; ++j) {
        long r = row0 + wm * 64 + mf * 16 + crow + j;
        long c = col0 + wn * 64 + nf * 16 + ccol;
        C[(long)blockIdx.z * sC + r * N + c] = acc[mf][nf][j] * alpha;
      }
}

// ---------------------------------------------------------------------------
// prep_index: grid (512, 4).
// ---------------------------------------------------------------------------
__global__ __launch_bounds__(256) void prep_index(
    const float* __restrict__ x,
    const float* __restrict__ s0, const float* __restrict__ s1,
    const float* __restrict__ s2,
    __bf16* __restrict__ hiB, __bf16* __restrict__ loB, long dstride,
    __bf16* __restrict__ xhi, __bf16* __restrict__ xlo)
{
  __shared__ float tile[64][65];
  int z = blockIdx.y;
  int tid = threadIdx.x;
  if (z < 3) {
    const int R = 2048, Cc = 1024;
    const float* in = (z == 0) ? s0 : (z == 1) ? s1 : s2;
    __bf16* hiT = hiB + (long)z * dstride;
    __bf16* loT = loB + (long)z * dstride;
    int f = blockIdx.x;
    int r0 = (f >> 4) * 64, c0 = (f & 15) * 64;
    #pragma unroll
    for (int j = 0; j < 16; ++j) {
      int idx = tid + j * 256;
      int r = idx >> 6, c = idx & 63;
      tile[r][c] = in[(long)(r0 + r) * Cc + c0 + c];
    }
    __syncthreads();
    #pragma unroll
    for (int j = 0; j < 16; ++j) {
      int idx = tid + j * 256;
      int c = idx >> 6, r = idx & 63;
      float v = tile[r][c];
      __bf16 h = (__bf16)v;
      hiT[(long)(c0 + c) * R + r0 + r] = h;
      loT[(long)(c0 + c) * R + r0 + r] = (__bf16)(v - (float)h);
    }
  } else {
    for (long i = ((long)blockIdx.x * 256 + tid) * 4; i < 8388608; i += 524288) {
      float4 v = *(const float4*)&x[i];
      bf16x4 h, l;
      h[0] = (__bf16)v.x; l[0] = (__bf16)(v.x - (float)h[0]);
      h[1] = (__bf16)v.y; l[1] = (__bf16)(v.y - (float)h[1]);
      h[2] = (__bf16)v.z; l[2] = (__bf16)(v.z - (float)h[2]);
      h[3] = (__bf16)v.w; l[3] = (__bf16)(v.w - (float)h[3]);
      *(bf16x4*)&xhi[i] = h;
      *(bf16x4*)&xlo[i] = l;
    }
  }
}

// ---------------------------------------------------------------------------
// prep_main: grid (512, 7).
// ---------------------------------------------------------------------------
__global__ __launch_bounds__(256) void prep_main(
    const float* __restrict__ s0, const float* __restrict__ s1,
    const float* __restrict__ s2, const float* __restrict__ s3,
    const float* __restrict__ s4, const float* __restrict__ s5,
    const float* __restrict__ wa,
    __bf16* __restrict__ W, long W2, __bf16* __restrict__ owab)
{
  __shared__ float tile[64][65];
  int z = blockIdx.y;
  int tid = threadIdx.x;
  if (z < 6) {
    int R, Cc, r0, c0;
    const float* in;
    if (z < 4) {
      R = 2048; Cc = 1024;
      in = (z == 0) ? s0 : (z == 1) ? s1 : (z == 2) ? s2 : s3;
      r0 = (blockIdx.x >> 4) * 64; c0 = (blockIdx.x & 15) * 64;
    } else {
      R = 1024; Cc = 2048;
      in = (z == 4) ? s4 : s5;
      r0 = (blockIdx.x >> 5) * 64; c0 = (blockIdx.x & 31) * 64;
    }
    __bf16* out = W + (long)z * W2;
    #pragma unroll
    for (int j = 0; j < 16; ++j) {
      int idx = tid + j * 256;
      int r = idx >> 6, c = idx & 63;
      tile[r][c] = in[(long)(r0 + r) * Cc + c0 + c];
    }
    __syncthreads();
    #pragma unroll
    for (int j = 0; j < 16; ++j) {
      int idx = tid + j * 256;
      int c = idx >> 6, r = idx & 63;
      out[(long)(c0 + c) * R + r0 + r] = (__bf16)tile[r][c];
    }
  } else {
    for (long i = ((long)blockIdx.x * 256 + tid) * 4; i < 2097152; i += 524288) {
      float4 v = *(const float4*)&wa[i];
      bf16x4 o;
      o[0] = (__bf16)v.x; o[1] = (__bf16)v.y; o[2] = (__bf16)v.z; o[3] = (__bf16)v.w;
      *(bf16x4*)&owab[i] = o;
    }
  }
}

// ---------------------------------------------------------------------------
// Group softmax over RATIO=4 + weighted sum + fused partial-RoPE on ck.
// ---------------------------------------------------------------------------
__global__ __launch_bounds__(256) void reduce_ckcv(
    const float* __restrict__ base, const float* __restrict__ c_ape,
    const float* __restrict__ cosb, const float* __restrict__ sinb,
    __bf16* __restrict__ ckb, __bf16* __restrict__ cvb)
{
  __shared__ float sck[256];
  const long S = 3072;
  int tid = threadIdx.x;
  int c = blockIdx.x * 256 + tid;
  int g = blockIdx.y, b = blockIdx.z;
  long row0 = (long)b * Tn + 4 * g;
  float lg[4], mx = -1e30f;
  #pragma unroll
  for (int r = 0; r < 4; ++r) {
    lg[r] = base[(row0 + r) * S + 2048 + c] + c_ape[r * 1024 + c];
    mx = fmaxf(mx, lg[r]);
  }
  float ssum = 0.f;
  #pragma unroll
  for (int r = 0; r < 4; ++r) { lg[r] = expf(lg[r] - mx); ssum += lg[r]; }
  float inv = 1.f / ssum, ak = 0.f, av = 0.f;
  #pragma unroll
  for (int r = 0; r < 4; ++r) {
    float w = lg[r] * inv;
    ak = fmaf(base[(row0 + r) * S + c],        w, ak);
    av = fmaf(base[(row0 + r) * S + 1024 + c], w, av);
  }
  long o = ((long)b * Gn + g) * 1024 + c;
  cvb[o] = (__bf16)av;
  sck[tid] = ak;
  __syncthreads();
  int d = c & 127;
  float outk = ak;
  if (d >= 64) {
    int t = 4 * g + 3;
    if (d < 96) {
      int j = d - 64;
      outk = ak * cosb[t * 64 + j] + sck[tid + 32] * sinb[t * 64 + j];
    } else {
      int j = d - 96;
      outk = -sck[tid - 32] * sinb[t * 64 + j] + ak * cosb[t * 64 + j];
    }
  }
  ckb[o] = (__bf16)outk;
}

// ---------------------------------------------------------------------------
// Fused index-path reducer: blocks <1024 do ikeys; blocks >=1024 do iq RMS.
// ---------------------------------------------------------------------------
__global__ __launch_bounds__(1024) void reduce_idx_fused(
    const float* __restrict__ base, const float* __restrict__ i_ape,
    __bf16* __restrict__ khi, __bf16* __restrict__ klo,
    __bf16* __restrict__ qhi, __bf16* __restrict__ qlo)
{
  const long S = 3072;
  int tid = threadIdx.x;
  int bid = blockIdx.x;
  if (bid < Gn * Bn) {
    int g = bid & (Gn - 1), b = bid >> 9;
    long row0 = (long)b * Tn + 4 * g;
    float lg[4], mx = -1e30f;
    #pragma unroll
    for (int r = 0; r < 4; ++r) {
      lg[r] = base[(row0 + r) * S + 1024 + tid] + i_ape[r * 1024 + tid];
      mx = fmaxf(mx, lg[r]);
    }
    float ssum = 0.f;
    #pragma unroll
    for (int r = 0; r < 4; ++r) { lg[r] = expf(lg[r] - mx); ssum += lg[r]; }
    float inv = 1.f / ssum, red = 0.f;
    #pragma unroll
    for (int r = 0; r < 4; ++r) red = fmaf(base[(row0 + r) * S + tid], lg[r] * inv, red);
    float ss = red * red;
    #pragma unroll
    for (int o = 32; o; o >>= 1) ss += __shfl_xor(ss, o);
    float v = red * rsqrtf(ss * (1.f / 64.f) + 1e-6f);
    long oi = ((long)b * Gn + g) * 1024 + tid;
    __bf16 h = (__bf16)v;
    khi[oi] = h; klo[oi] = (__bf16)(v - (float)h);
  } else {
    long row = bid - Gn * Bn;
    float v = base[row * S + 2048 + tid];
    float ss = v * v;
    #pragma unroll
    for (int o = 32; o; o >>= 1) ss += __shfl_xor(ss, o);
    float y = v * rsqrtf(ss * (1.f / 64.f) + 1e-6f);
    __bf16 h = (__bf16)y;
    qhi[row * 1024 + tid] = h;
    qlo[row * 1024 + tid] = (__bf16)(y - (float)h);
  }
}

// ---------------------------------------------------------------------------
// Per-row rms scales from bf16 h.
// ---------------------------------------------------------------------------
__global__ __launch_bounds__(256) void rms_scales(
    const __bf16* __restrict__ h, float* __restrict__ rs)
{
  int wid = threadIdx.x >> 6, lane = threadIdx.x & 63;
  long row = (long)blockIdx.x * 4 + wid;
  const __bf16* hr = h + row * 1024 + lane * 16;
  bf16x8 a = *(const bf16x8*)hr;
  bf16x8 b = *(const bf16x8*)(hr + 8);
  float ss = 0.f;
  #pragma unroll
  for (int j = 0; j < 8; ++j) {
    float x = (float)a[j], y = (float)b[j];
    ss = fmaf(x, x, ss); ss = fmaf(y, y, ss);
  }
  #pragma unroll
  for (int o = 1; o < 64; o <<= 1) ss += __shfl_xor(ss, o);
  if (lane == 0) rs[row] = rsqrtf(ss * (1.f / 1024.f) + 1e-6f);
}

// ---------------------------------------------------------------------------
__global__ __launch_bounds__(256) void topk_kernel(
    const float* __restrict__ iscore, int* __restrict__ selidx, int* __restrict__ selcnt)
{
  int wave = threadIdx.x >> 6, lane = threadIdx.x & 63;
  long bt = (long)blockIdx.x * 4 + wave;
  int t = (int)(bt % Tn);
  const float* row = iscore + bt * Gn;
  int ng = (t + 1) >> 2; if (ng > Gn) ng = Gn;
  int cap = ng < TKn ? ng : TKn;
  float s[8];
  #pragma unroll
  for (int j = 0; j < 8; ++j) {
    int g = lane + 64 * j;
    s[j] = (g < ng) ? row[g] : -INFINITY;
  }
  int* outp = selidx + bt * TKn;
  for (int it = 0; it < cap; ++it) {
    float bv = -INFINITY; int bi = Gn;
    #pragma unroll
    for (int j = 0; j < 8; ++j) {
      int g = lane + 64 * j;
      if (s[j] > bv) { bv = s[j]; bi = g; }
    }
    #pragma unroll
    for (int o = 1; o < 64; o <<= 1) {
      float ov = __shfl_xor(bv, o); int oi = __shfl_xor(bi, o);
      if (ov > bv || (ov == bv && oi < bi)) { bv = ov; bi = oi; }
    }
    if (lane == 0) outp[it] = bi;
    #pragma unroll
    for (int j = 0; j < 8; ++j) if (bi == lane + 64 * j) s[j] = -INFINITY;
  }
  for (int it = cap + lane; it < TKn; it += 64) outp[it] = 0;
  if (lane == 0) selcnt[bt] = cap;
}

// ---------------------------------------------------------------------------
// Gathered sink-softmax attention v8: one wave per (b,t), all 16 heads.
// ---------------------------------------------------------------------------
__global__ __launch_bounds__(256) void attn_kernel(
    const __bf16* __restrict__ q, const __bf16* __restrict__ ckb,
    const __bf16* __restrict__ cvb, const int* __restrict__ selidx,
    const int* __restrict__ selcnt, const float* __restrict__ sink,
    __bf16* __restrict__ out)
{
  __shared__ float sS[4][16][68];
  __shared__ int   sG[4][64];
  const float scale = 0.08838834764831845f;
  int wid = threadIdx.x >> 6, lane = threadIdx.x & 63;
  long bt = (long)blockIdx.x * 4 + wid;
  int b = (int)(bt >> 11);
  int cnt = selcnt[bt];
  int gid = (lane < cnt) ? selidx[bt * TKn + lane] : 0;
  sG[wid][lane] = gid;

  int grp = lane >> 3;
  int sub = lane & 7;
  int h0 = grp * 2, h1 = h0 + 1;
  int d0 = sub * 16;

  const __bf16* qrow = q + bt * 2048;
  float q0[16], q1[16];
  {
    bf16x8 a0 = *(const bf16x8*)&qrow[h0 * 128 + d0];
    bf16x8 a1 = *(const bf16x8*)&qrow[h0 * 128 + d0 + 8];
    bf16x8 c0 = *(const bf16x8*)&qrow[h1 * 128 + d0];
    bf16x8 c1 = *(const bf16x8*)&qrow[h1 * 128 + d0 + 8];
    #pragma unroll
    for (int j = 0; j < 8; ++j) {
      q0[j] = (float)a0[j]; q0[8 + j] = (float)a1[j];
      q1[j] = (float)c0[j]; q1[8 + j] = (float)c1[j];
    }
  }
  __syncthreads();

  for (int i0 = 0; i0 < 64; i0 += 8) {
    #pragma unroll
    for (int u = 0; u < 8; ++u) {
      int i = i0 + u;
      int g = sG[wid][i];
      const __bf16* kr = ckb + ((long)(b * Gn + g)) * 1024 + lane * 16;
      bf16x8 k0 = *(const bf16x8*)kr;
      bf16x8 k1 = *(const bf16x8*)(kr + 8);
      float p0 = 0.f, p1 = 0.f;
      #pragma unroll
      for (int j = 0; j < 8; ++j) {
        float kv = (float)k0[j];
        p0 = fmaf(kv, q0[j], p0); p1 = fmaf(kv, q1[j], p1);
      }
      #pragma unroll
      for (int j = 0; j < 8; ++j) {
        float kv = (float)k1[j];
        p0 = fmaf(kv, q0[8 + j], p0); p1 = fmaf(kv, q1[8 + j], p1);
      }
      p0 += __shfl_xor(p0, 1); p0 += __shfl_xor(p0, 2); p0 += __shfl_xor(p0, 4);
      p1 += __shfl_xor(p1, 1); p1 += __shfl_xor(p1, 2); p1 += __shfl_xor(p1, 4);
      if (sub == 0) { sS[wid][h0][i] = p0; sS[wid][h1][i] = p1; }
    }
  }
  __syncthreads();

  {
    int h = lane >> 2, qtr = lane & 3;
    float sv[16];
    float mx = -INFINITY;
    #pragma unroll
    for (int j = 0; j < 16; ++j) {
      int i = qtr * 16 + j;
      float s = (i < cnt) ? sS[wid][h][i] * scale : -INFINITY;
      sv[j] = s; mx = fmaxf(mx, s);
    }
    mx = fmaxf(mx, __shfl_xor(mx, 1));
    mx = fmaxf(mx, __shfl_xor(mx, 2));
    float snk = sink[h];
    mx = fmaxf(mx, snk);
    float sum = 0.f;
    #pragma unroll
    for (int j = 0; j < 16; ++j) { sv[j] = __expf(sv[j] - mx); sum += sv[j]; }
    sum += __shfl_xor(sum, 1);
    sum += __shfl_xor(sum, 2);
    sum += __expf(snk - mx);
    float inv = 1.f / sum;
    #pragma unroll
    for (int j = 0; j < 16; ++j) sS[wid][h][qtr * 16 + j] = sv[j] * inv;
  }
  __syncthreads();

  float o0[16], o1[16];
  #pragma unroll
  for (int j = 0; j < 16; ++j) { o0[j] = 0.f; o1[j] = 0.f; }
  for (int i0 = 0; i0 < 64; i0 += 8) {
    #pragma unroll
    for (int u = 0; u < 8; ++u) {
      int i = i0 + u;
      int g = sG[wid][i];
      float p0 = sS[wid][h0][i], p1 = sS[wid][h1][i];
      const __bf16* vr = cvb + ((long)(b * Gn + g)) * 1024 + lane * 16;
      bf16x8 v0 = *(const bf16x8*)vr;
      bf16x8 v1 = *(const bf16x8*)(vr + 8);
      #pragma unroll
      for (int j = 0; j < 8; ++j) {
        float vv = (float)v0[j];
        o0[j] = fmaf(p0, vv, o0[j]); o1[j] = fmaf(p1, vv, o1[j]);
      }
      #pragma unroll
      for (int j = 0; j < 8; ++j) {
        float vv = (float)v1[j];
        o0[8 + j] = fmaf(p0, vv, o0[8 + j]); o1[8 + j] = fmaf(p1, vv, o1[8 + j]);
      }
    }
  }
  __bf16* ob = out + bt * 2048;
  bf16x8 w;
  #pragma unroll
  for (int j = 0; j < 8; ++j) w[j] = (__bf16)o0[j];
  *(bf16x8*)&ob[h0 * 128 + d0] = w;
  #pragma unroll
  for (int j = 0; j < 8; ++j) w[j] = (__bf16)o0[8 + j];
  *(bf16x8*)&ob[h0 * 128 + d0 + 8] = w;
  #pragma unroll
  for (int j = 0; j < 8; ++j) w[j] = (__bf16)o1[j];
  *(bf16x8*)&ob[h1 * 128 + d0] = w;
  #pragma unroll
  for (int j = 0; j < 8; ++j) w[j] = (__bf16)o1[8 + j];
  *(bf16x8*)&ob[h1 * 128 + d0 + 8] = w;
}

// ---------------------------------------------------------------------------
extern "C" void kernel_launch(void* const* d_in, const int* in_sizes, int n_in,
                              void* d_out, int out_size, void* d_ws, size_t ws_size,
                              hipStream_t stream) {
  const float* x     = (const float*)d_in[0];
  const float* cosb  = (const float*)d_in[1];
  const float* sinb  = (const float*)d_in[2];
  const float* q_a_w = (const float*)d_in[3];
  const float* q_b_w = (const float*)d_in[4];
  const float* ck_w  = (const float*)d_in[5];
  const float* cv_w  = (const float*)d_in[6];
  const float* cg_w  = (const float*)d_in[7];
  const float* c_ape = (const float*)d_in[8];
  const float* iq_w  = (const float*)d_in[9];
  const float* ik_w  = (const float*)d_in[10];
  const float* ig_w  = (const float*)d_in[11];
  const float* i_ape = (const float*)d_in[12];
  const float* sink  = (const float*)d_in[13];
  const float* o_wa  = (const float*)d_in[14];
  const float* o_pb  = (const float*)d_in[15];
  float* outp = (float*)d_out;
  float* ws = (float*)d_ws;

  const long F  = 4194304;
  const long M1 = 1048576;

  float* b_all = ws;
  float*  iscore = ws + F;
  __bf16* oatt_b = (__bf16*)(ws + F);
  __bf16* hb_b   = (__bf16*)ws;            // bf16 h (out-proj output)

  // d_out overlays (time-disjoint, stream-serialized):
  __bf16* iq_hi = (__bf16*)d_out;
  __bf16* iq_lo = (__bf16*)d_out + 4194304;
  __bf16* qb    = (__bf16*)d_out;          // bf16 q (after selection phase)

  char* tp = (char*)(ws + 3 * F);
  __bf16* ckb = (__bf16*)tp;     tp += (size_t)M1 * 4;
  __bf16* cvb = (__bf16*)tp;     tp += (size_t)M1 * 4;
  int*   selidx = (int*)tp;      tp += 2097152;
  int*   selcnt = selidx + Bn * Tn * TKn;
  __bf16* ikeys_hi = (__bf16*)tp; tp += 2097152;
  __bf16* ikeys_lo = (__bf16*)tp; tp += 2097152;
  __bf16* xhi = (__bf16*)tp;      tp += 16777216;
  __bf16* xlo = (__bf16*)tp;      tp += 16777216;
  __bf16* W   = (__bf16*)tp;      tp += 7 * 4194304;
  __bf16* qa_buf = (__bf16*)tp;   tp += 8388608;
  float*  rs     = (float*)tp;    tp += 16384;          // 4096 f32 scales
  const long W2 = 2097152;
  __bf16* Whi = W;            __bf16* Wlo = W + 3 * W2;
  __bf16* ckT  = W;           // ck|cv|cg|qa contiguous (phase-2 overlay)
  __bf16* qbT  = W + 4*W2;
  __bf16* opbT = W + 5*W2;   __bf16* owab = W + 6*W2;

  // ---- merged conversions: index path ----
  prep_index<<<dim3(512, 4), 256, 0, stream>>>(
      x, ik_w, ig_w, iq_w, Whi, Wlo, W2, xhi, xlo);

  // ---- index path: split GEMM (R23: 128x192 3-phase, 2 blocks/CU) ----
  gemm_split_2b<<<dim3(16, 32), 256, 0, stream>>>(xhi, xlo, Whi, Wlo, b_all,
      4096, 3072, 2048, 1.f);
  reduce_idx_fused<<<dim3(Gn * Bn + Bn * Tn), 1024, 0, stream>>>(
      b_all, i_ape, ikeys_hi, ikeys_lo, iq_hi, iq_lo);

  // ---- selection (R19 pipelined split GEMM) ----
  gemm_split<<<dim3(4, 16, 2), 256, 0, stream>>>(iq_hi, iq_lo, ikeys_hi, ikeys_lo, iscore,
      2048, 512, 1024, 1.f / 128.f, (long)2048 * 1024, (long)512 * 1024, (long)2048 * 512);
  topk_kernel<<<dim3(Bn * Tn / 4), 256, 0, stream>>>(iscore, selidx, selcnt);

  // ---- merged conversions: main-path weights ----
  prep_main<<<dim3(512, 7), 256, 0, stream>>>(
      ck_w, cv_w, cg_w, q_a_w, q_b_w, o_pb, o_wa, W, W2, owab);

  // ---- merged kv+qa GEMM (R20: 256x256 8-phase, grid 256 = 1/CU) ----
  gemm_kvqa_8ph<<<dim3(16, 16), 512, 0, stream>>>(xhi, ckT, b_all, qa_buf);
  reduce_ckcv<<<dim3(4, Gn, Bn), 256, 0, stream>>>(b_all, c_ape, cosb, sinb, ckb, cvb);

  // ---- q GEMM (pipelined, fused rope epilogue) -> bf16 q (d_out) ----
  gemm_pipe<1><<<dim3(16, 32), 256, 0, stream>>>(
      qa_buf, qbT, qb, 2048, 1024, cosb, sinb, nullptr);

  // ---- attention v8 (bf16 q) ----
  attn_kernel<<<dim3(Bn * Tn / 4), 256, 0, stream>>>(qb, ckb, cvb, selidx, selcnt, sink, oatt_b);

  // ---- output projection (pipelined, bf16 h direct) ----
  gemm_pipe<0><<<dim3(8, 32), 256, 0, stream>>>(
      oatt_b, owab, hb_b, 1024, 2048, nullptr, nullptr, nullptr);
  rms_scales<<<dim3(1024), 256, 0, stream>>>(hb_b, rs);
  // ---- final GEMM (pipelined, fused rms row scales) ----
  gemm_pipe<2><<<dim3(16, 32), 256, 0, stream>>>(
      hb_b, opbT, outp, 2048, 1024, nullptr, nullptr, rs);
}

// Round 6
// 508.044 us; speedup vs baseline: 1.0559x; 1.0559x over previous
//
#include <hip/hip_runtime.h>
#include <hip/hip_bf16.h>
#include <math.h>

constexpr int Bn  = 2;
constexpr int Tn  = 2048;
constexpr int NHn = 16;
constexpr int NKVn= 8;
constexpr int Gn  = 512;
constexpr int TKn = 64;

typedef __attribute__((ext_vector_type(8))) __bf16 bf16x8;
typedef __attribute__((ext_vector_type(4))) __bf16 bf16x4;
typedef __attribute__((ext_vector_type(2))) __bf16 bf16x2;
typedef __attribute__((ext_vector_type(4))) float f32x4;

__device__ __forceinline__ void gload_lds16(const void* g, void* l) {
  __builtin_amdgcn_global_load_lds(
      (const __attribute__((address_space(1))) unsigned int*)g,
      (__attribute__((address_space(3))) unsigned int*)l, 16, 0, 0);
}

// ---------------------------------------------------------------------------
// gemm_kvqa_8ph (R20): 256x256 tile, 8 waves, BK=64 (2 sub-phases of 32),
// 4 phases per K-tile with counted vmcnt(4) (never 0 in steady state),
// double-buffered 128 KiB LDS, proven c4^((r>>1)&3) swizzle (0 conflicts).
// ---------------------------------------------------------------------------
__global__ __launch_bounds__(512) void gemm_kvqa_8ph(
    const __bf16* __restrict__ A, const __bf16* __restrict__ Bt,
    float* __restrict__ Cf, __bf16* __restrict__ Cq)
{
  constexpr int K = 2048;
  constexpr int NT = K / 64;                  // 32 K-tiles
  __shared__ __bf16 lds[2][2][2][256][32];    // [buf][op A/B][ph][row][col] = 128 KiB
  const int tid = threadIdx.x;
  const int wid = tid >> 6, lane = tid & 63;
  const int wm = wid >> 2, wn = wid & 3;      // 2 (M) x 4 (N) wave grid
  const int row0 = blockIdx.y * 256, col0 = blockIdx.x * 256;

  f32x4 acc[8][4];
  const f32x4 zero = {0.f, 0.f, 0.f, 0.f};
  #pragma unroll
  for (int i = 0; i < 8; ++i)
    #pragma unroll
    for (int j = 0; j < 4; ++j) acc[i][j] = zero;

  // stage one (op, ph) half-tile (256 rows x 32 cols) of K-tile kt into buf
  auto stage1 = [&](int kt, int op, int ph, int buf) {
    long k0 = (long)kt * 64 + ph * 32;
    const __bf16* src = op ? Bt : A;
    const int base0 = op ? col0 : row0;
    #pragma unroll
    for (int l = 0; l < 2; ++l) {
      int u = l * 512 + tid;
      int r = u >> 2, c4 = u & 3;
      long csrc = (long)((c4 ^ ((r >> 1) & 3)) * 8);
      gload_lds16(src + (long)(base0 + r) * K + k0 + csrc, &lds[buf][op][ph][r][c4 * 8]);
    }
  };

  // prologue: stage kt0 halves H0..H3 = (A,0),(B,0),(A,1),(B,1)
  stage1(0, 0, 0, 0);
  stage1(0, 1, 0, 0);
  stage1(0, 0, 1, 0);
  stage1(0, 1, 1, 0);
  asm volatile("s_waitcnt vmcnt(4)" ::: "memory");   // H0,H1 done; H2,H3 in flight
  asm volatile("s_barrier" ::: "memory");

  for (int kt = 0; kt < NT; ++kt) {
    const int buf = kt & 1;
    const bool pre = (kt + 1 < NT);
    bf16x8 afA[4], afB[4], bf[4];

    // ---- P0: ph0, acc rows mf0-3 ----
    #pragma unroll
    for (int i = 0; i < 4; ++i) {
      int r = wm * 128 + i * 16 + (lane & 15);
      int c4 = (lane >> 4) ^ ((r >> 1) & 3);
      afA[i] = *(const bf16x8*)&lds[buf][0][0][r][c4 * 8];
    }
    #pragma unroll
    for (int i = 0; i < 4; ++i) {
      int r = wn * 64 + i * 16 + (lane & 15);
      int c4 = (lane >> 4) ^ ((r >> 1) & 3);
      bf[i] = *(const bf16x8*)&lds[buf][1][0][r][c4 * 8];
    }
    if (pre) stage1(kt + 1, 0, 0, buf ^ 1);
    asm volatile("s_barrier" ::: "memory");
    asm volatile("s_waitcnt lgkmcnt(0)" ::: "memory");
    __builtin_amdgcn_sched_barrier(0);
    __builtin_amdgcn_s_setprio(1);
    #pragma unroll
    for (int i = 0; i < 4; ++i)
      #pragma unroll
      for (int j = 0; j < 4; ++j)
        acc[i][j] = __builtin_amdgcn_mfma_f32_16x16x32_bf16(afA[i], bf[j], acc[i][j], 0, 0, 0);
    __builtin_amdgcn_s_setprio(0);
    asm volatile("s_barrier" ::: "memory");

    // ---- P1: ph0, acc rows mf4-7 ----
    #pragma unroll
    for (int i = 0; i < 4; ++i) {
      int r = wm * 128 + (i + 4) * 16 + (lane & 15);
      int c4 = (lane >> 4) ^ ((r >> 1) & 3);
      afB[i] = *(const bf16x8*)&lds[buf][0][0][r][c4 * 8];
    }
    if (pre) {
      stage1(kt + 1, 1, 0, buf ^ 1);
      asm volatile("s_waitcnt vmcnt(4)" ::: "memory");  // confirm kt.H2,H3
    } else {
      asm volatile("s_waitcnt vmcnt(0)" ::: "memory");
    }
    asm volatile("s_barrier" ::: "memory");
    asm volatile("s_waitcnt lgkmcnt(0)" ::: "memory");
    __builtin_amdgcn_sched_barrier(0);
    __builtin_amdgcn_s_setprio(1);
    #pragma unroll
    for (int i = 0; i < 4; ++i)
      #pragma unroll
      for (int j = 0; j < 4; ++j)
        acc[i + 4][j] = __builtin_amdgcn_mfma_f32_16x16x32_bf16(afB[i], bf[j], acc[i + 4][j], 0, 0, 0);
    __builtin_amdgcn_s_setprio(0);
    asm volatile("s_barrier" ::: "memory");

    // ---- P2: ph1, acc rows mf0-3 ----
    #pragma unroll
    for (int i = 0; i < 4; ++i) {
      int r = wm * 128 + i * 16 + (lane & 15);
      int c4 = (lane >> 4) ^ ((r >> 1) & 3);
      afA[i] = *(const bf16x8*)&lds[buf][0][1][r][c4 * 8];
    }
    #pragma unroll
    for (int i = 0; i < 4; ++i) {
      int r = wn * 64 + i * 16 + (lane & 15);
      int c4 = (lane >> 4) ^ ((r >> 1) & 3);
      bf[i] = *(const bf16x8*)&lds[buf][1][1][r][c4 * 8];
    }
    if (pre) stage1(kt + 1, 0, 1, buf ^ 1);
    asm volatile("s_barrier" ::: "memory");
    asm volatile("s_waitcnt lgkmcnt(0)" ::: "memory");
    __builtin_amdgcn_sched_barrier(0);
    __builtin_amdgcn_s_setprio(1);
    #pragma unroll
    for (int i = 0; i < 4; ++i)
      #pragma unroll
      for (int j = 0; j < 4; ++j)
        acc[i][j] = __builtin_amdgcn_mfma_f32_16x16x32_bf16(afA[i], bf[j], acc[i][j], 0, 0, 0);
    __builtin_amdgcn_s_setprio(0);
    asm volatile("s_barrier" ::: "memory");

    // ---- P3: ph1, acc rows mf4-7 ----
    #pragma unroll
    for (int i = 0; i < 4; ++i) {
      int r = wm * 128 + (i + 4) * 16 + (lane & 15);
      int c4 = (lane >> 4) ^ ((r >> 1) & 3);
      afB[i] = *(const bf16x8*)&lds[buf][0][1][r][c4 * 8];
    }
    if (pre) {
      stage1(kt + 1, 1, 1, buf ^ 1);
      asm volatile("s_waitcnt vmcnt(4)" ::: "memory");  // confirm kt+1.H0,H1
    }
    asm volatile("s_barrier" ::: "memory");
    asm volatile("s_waitcnt lgkmcnt(0)" ::: "memory");
    __builtin_amdgcn_sched_barrier(0);
    __builtin_amdgcn_s_setprio(1);
    #pragma unroll
    for (int i = 0; i < 4; ++i)
      #pragma unroll
      for (int j = 0; j < 4; ++j)
        acc[i + 4][j] = __builtin_amdgcn_mfma_f32_16x16x32_bf16(afB[i], bf[j], acc[i + 4][j], 0, 0, 0);
    __builtin_amdgcn_s_setprio(0);
    asm volatile("s_barrier" ::: "memory");
  }

  const int crow = (lane >> 4) * 4, ccol = lane & 15;
  const bool isQ = (col0 >= 3072);
  #pragma unroll
  for (int mf = 0; mf < 8; ++mf)
    #pragma unroll
    for (int nf = 0; nf < 4; ++nf)
      #pragma unroll
      for (int j = 0; j < 4; ++j) {
        long r = row0 + wm * 128 + mf * 16 + crow + j;
        long c = col0 + wn * 64 + nf * 16 + ccol;
        float v = acc[mf][nf][j];
        if (isQ) Cq[r * 1024 + (c - 3072)] = (__bf16)v;
        else     Cf[r * 3072 + c] = v;
      }
}

// ---------------------------------------------------------------------------
// gemm_split_flat (R24): 3-product split GEMM, 256x192 tile, 8 waves (2Mx4N),
// BK=32, FLAT kt body: counted vmcnt(7) + ONE barrier at kt start, then all
// 22 fragment ds_reads + all 72 MFMAs in one region with NO intermediate
// lgkmcnt(0)/sched_barrier/barriers -> compiler emits fine-grained lgkmcnt
// per dependency, so reads drain UNDER the MFMA stream (R21's 8 pinning
// points serialized LDS traffic against MFMA: time was sum, not max).
// One barrier at kt end fences reads before next kt's staging overwrites.
// Stages for kt+1 issued at top of kt (dest buffer fenced by kt-1's end
// barrier). Per-acc product order hh->hl->lh per K-slice == R19/R21/R22
// (bit-identical). Grid 16x16 = 256 blocks = 1/CU. LDS 112 KiB.
// ---------------------------------------------------------------------------
__global__ __launch_bounds__(512) void gemm_split_flat(
    const __bf16* __restrict__ Ah, const __bf16* __restrict__ Al,
    const __bf16* __restrict__ Bh, const __bf16* __restrict__ Bl,
    float* __restrict__ C, int M, int N, int K, float alpha)
{
  const int NT = K >> 5;                      // BK = 32
  constexpr int LA_H = 0;                     // 256*32 = 8192
  constexpr int LA_L = 8192;
  constexpr int LB_H = 16384;                 // Bh 192*32 = 6144, then Bl 6144
  constexpr int LBUF = 28672;                 // elems per buffer
  __shared__ __bf16 sm[2 * LBUF];             // 114688 B
  const int tid = threadIdx.x;
  const int wid = tid >> 6, lane = tid & 63;
  const int wm = wid >> 2, wn = wid & 3;      // 2 (M) x 4 (N)
  const int row0 = blockIdx.y * 256, col0 = blockIdx.x * 192;

  f32x4 acc[8][3];
  const f32x4 zero = {0.f, 0.f, 0.f, 0.f};
  #pragma unroll
  for (int i = 0; i < 8; ++i)
    #pragma unroll
    for (int j = 0; j < 3; ++j) acc[i][j] = zero;

  // A half-tile (256x32) of stream which (0=hi,1=lo): 2 loads/thread
  auto stageA = [&](int kt, int buf, int which) {
    long k0 = (long)kt * 32;
    const __bf16* src = which ? Al : Ah;
    __bf16* dst = &sm[buf * LBUF + (which ? LA_L : LA_H)];
    #pragma unroll
    for (int l = 0; l < 2; ++l) {
      int u = l * 512 + tid;
      int r = u >> 2, c4 = u & 3;
      long csrc = (long)((c4 ^ ((r >> 1) & 3)) * 8);
      gload_lds16(src + (long)(row0 + r) * K + k0 + csrc, dst + u * 8);
    }
  };
  // B combined half-tile (Bh 192x32 then Bl 192x32): 3 loads/thread
  auto stageB = [&](int kt, int buf) {
    long k0 = (long)kt * 32;
    __bf16* dst = &sm[buf * LBUF + LB_H];
    #pragma unroll
    for (int l = 0; l < 3; ++l) {
      int u = l * 512 + tid;
      int v = (u < 768) ? u : u - 768;
      const __bf16* src = (u < 768) ? Bh : Bl;
      int r = v >> 2, c4 = v & 3;
      long csrc = (long)((c4 ^ ((r >> 1) & 3)) * 8);
      gload_lds16(src + (long)(col0 + r) * K + k0 + csrc, dst + u * 8);
    }
  };

  // prologue: issue kt0's 7 staging loads; loop handles the wait.
  stageB(0, 0);
  stageA(0, 0, 0);
  stageA(0, 0, 1);

  for (int kt = 0; kt < NT; ++kt) {
    const int buf = kt & 1;
    const bool pre = (kt + 1 < NT);

    // issue kt+1's staging (7 loads) into buf^1 (fenced by kt-1's end barrier)
    if (pre) {
      stageB(kt + 1, buf ^ 1);
      stageA(kt + 1, buf ^ 1, 0);
      stageA(kt + 1, buf ^ 1, 1);
      asm volatile("s_waitcnt vmcnt(7)" ::: "memory");  // kt's 7 done; kt+1's in flight
    } else {
      asm volatile("s_waitcnt vmcnt(0)" ::: "memory");
    }
    asm volatile("s_barrier" ::: "memory");             // buf fully staged, all waves

    // ---- flat region: 22 ds_read_b128 + 72 MFMA, compiler-scheduled ----
    bf16x8 a_h[8], a_l[8], b_h[3], b_l[3];
    #pragma unroll
    for (int i = 0; i < 8; ++i) {
      int r = wm * 128 + i * 16 + (lane & 15);
      int c4 = (lane >> 4) ^ ((r >> 1) & 3);
      a_h[i] = *(const bf16x8*)&sm[buf * LBUF + LA_H + r * 32 + c4 * 8];
      a_l[i] = *(const bf16x8*)&sm[buf * LBUF + LA_L + r * 32 + c4 * 8];
    }
    #pragma unroll
    for (int j = 0; j < 3; ++j) {
      int r = wn * 48 + j * 16 + (lane & 15);
      int c4 = (lane >> 4) ^ ((r >> 1) & 3);
      b_h[j] = *(const bf16x8*)&sm[buf * LBUF + LB_H + r * 32 + c4 * 8];
      b_l[j] = *(const bf16x8*)&sm[buf * LBUF + LB_H + 6144 + r * 32 + c4 * 8];
    }
    __builtin_amdgcn_s_setprio(1);
    #pragma unroll
    for (int i = 0; i < 8; ++i)
      #pragma unroll
      for (int j = 0; j < 3; ++j) {
        acc[i][j] = __builtin_amdgcn_mfma_f32_16x16x32_bf16(a_h[i], b_h[j], acc[i][j], 0, 0, 0);
        acc[i][j] = __builtin_amdgcn_mfma_f32_16x16x32_bf16(a_h[i], b_l[j], acc[i][j], 0, 0, 0);
        acc[i][j] = __builtin_amdgcn_mfma_f32_16x16x32_bf16(a_l[i], b_h[j], acc[i][j], 0, 0, 0);
      }
    __builtin_amdgcn_s_setprio(0);
    __builtin_amdgcn_sched_barrier(0);
    asm volatile("s_barrier" ::: "memory");             // reads done before next staging
  }

  const int crow = (lane >> 4) * 4, ccol = lane & 15;
  #pragma unroll
  for (int mf = 0; mf < 8; ++mf)
    #pragma unroll
    for (int nf = 0; nf < 3; ++nf)
      #pragma unroll
      for (int j = 0; j < 4; ++j) {
        long r = row0 + wm * 128 + mf * 16 + crow + j;
        long c = col0 + wn * 48 + nf * 16 + ccol;
        C[r * N + c] = acc[mf][nf][j] * alpha;
      }
}

// ---------------------------------------------------------------------------
// Unified pipelined GEMM (R13 schedule, runtime K): C = A @ Bt^T.
// EPI 0: bf16 out.  EPI 1: rope bf16 q layout (N=2048).  EPI 2: f32 * rs[r].
// ---------------------------------------------------------------------------
template<int EPI>
__global__ __launch_bounds__(256) void gemm_pipe(
    const __bf16* __restrict__ A, const __bf16* __restrict__ Bt,
    void* __restrict__ Cp, int N, int K,
    const float* __restrict__ cosb, const float* __restrict__ sinb,
    const float* __restrict__ rs)
{
  const int NT = K >> 6;
  __shared__ __bf16 lds[2][2][2][128][32];
  const int tid = threadIdx.x;
  const int wid = tid >> 6, lane = tid & 63;
  const int wm = wid >> 1, wn = wid & 1;
  const int row0 = blockIdx.y * 128, col0 = blockIdx.x * 128;

  f32x4 acc[4][4];
  const f32x4 zero = {0.f, 0.f, 0.f, 0.f};
  #pragma unroll
  for (int i = 0; i < 4; ++i)
    #pragma unroll
    for (int j = 0; j < 4; ++j) acc[i][j] = zero;

  auto stage = [&](int kt, int p, int buf) {
    long k0 = (long)kt * 64 + p * 32;
    #pragma unroll
    for (int l = 0; l < 2; ++l) {
      int u = l * 256 + tid;
      int r = u >> 2, c4 = u & 3;
      long csrc = (long)((c4 ^ ((r >> 1) & 3)) * 8);
      gload_lds16(A  + (long)(row0 + r) * K + k0 + csrc, &lds[buf][0][p][r][c4 * 8]);
      gload_lds16(Bt + (long)(col0 + r) * K + k0 + csrc, &lds[buf][1][p][r][c4 * 8]);
    }
  };

  stage(0, 0, 0);
  stage(0, 1, 0);

  for (int kt = 0; kt < NT; ++kt) {
    const int buf = kt & 1;
    #pragma unroll
    for (int ph = 0; ph < 2; ++ph) {
      if (kt + 1 < NT) {
        stage(kt + 1, ph, buf ^ 1);
        asm volatile("s_waitcnt vmcnt(8)" ::: "memory");
      } else {
        if (ph == 0) asm volatile("s_waitcnt vmcnt(4)" ::: "memory");
        else         asm volatile("s_waitcnt vmcnt(0)" ::: "memory");
      }
      asm volatile("s_barrier" ::: "memory");
      bf16x8 af[4], bfr[4];
      #pragma unroll
      for (int mf = 0; mf < 4; ++mf) {
        int r = wm * 64 + mf * 16 + (lane & 15);
        int c4 = (lane >> 4) ^ ((r >> 1) & 3);
        af[mf] = *(const bf16x8*)&lds[buf][0][ph][r][c4 * 8];
      }
      #pragma unroll
      for (int nf = 0; nf < 4; ++nf) {
        int r = wn * 64 + nf * 16 + (lane & 15);
        int c4 = (lane >> 4) ^ ((r >> 1) & 3);
        bfr[nf] = *(const bf16x8*)&lds[buf][1][ph][r][c4 * 8];
      }
      __builtin_amdgcn_s_setprio(1);
      #pragma unroll
      for (int mf = 0; mf < 4; ++mf)
        #pragma unroll
        for (int nf = 0; nf < 4; ++nf)
          acc[mf][nf] = __builtin_amdgcn_mfma_f32_16x16x32_bf16(af[mf], bfr[nf], acc[mf][nf], 0, 0, 0);
      __builtin_amdgcn_s_setprio(0);
      asm volatile("s_barrier" ::: "memory");
    }
  }

  const int crow = (lane >> 4) * 4, ccol = lane & 15;
  if constexpr (EPI == 1) {
    __bf16* C = (__bf16*)Cp;
    if (wn == 1) {
      #pragma unroll
      for (int mf = 0; mf < 4; ++mf)
        #pragma unroll
        for (int j = 0; j < 4; ++j) {
          long r = row0 + wm * 64 + mf * 16 + crow + j;
          int t = (int)(r & 2047);
          #pragma unroll
          for (int nfp = 0; nfp < 2; ++nfp) {
            int jj = nfp * 16 + ccol;
            float c = cosb[t * 64 + jj], s = sinb[t * 64 + jj];
            float x1 = acc[mf][nfp][j];
            float x2 = acc[mf][nfp + 2][j];
            C[r * N + col0 + 64 + jj] = (__bf16)(x1 * c + x2 * s);
            C[r * N + col0 + 96 + jj] = (__bf16)(-x1 * s + x2 * c);
          }
        }
    } else {
      #pragma unroll
      for (int mf = 0; mf < 4; ++mf)
        #pragma unroll
        for (int nf = 0; nf < 4; ++nf)
          #pragma unroll
          for (int j = 0; j < 4; ++j) {
            long r = row0 + wm * 64 + mf * 16 + crow + j;
            long c = col0 + nf * 16 + ccol;
            C[r * N + c] = (__bf16)acc[mf][nf][j];
          }
    }
  } else {
    #pragma unroll
    for (int mf = 0; mf < 4; ++mf)
      #pragma unroll
      for (int nf = 0; nf < 4; ++nf)
        #pragma unroll
        for (int j = 0; j < 4; ++j) {
          long r = row0 + wm * 64 + mf * 16 + crow + j;
          long c = col0 + wn * 64 + nf * 16 + ccol;
          float v = acc[mf][nf][j];
          if constexpr (EPI == 2)
            ((float*)Cp)[r * N + c] = v * rs[r];
          else
            ((__bf16*)Cp)[r * N + c] = (__bf16)v;
        }
  }
}

// ---------------------------------------------------------------------------
// Split-precision GEMM, R19 (kept for the small selection GEMM).
// ---------------------------------------------------------------------------
__global__ __launch_bounds__(256) void gemm_split(
    const __bf16* __restrict__ Ah, const __bf16* __restrict__ Al,
    const __bf16* __restrict__ Bh, const __bf16* __restrict__ Bl,
    float* __restrict__ C, int M, int N, int K, float alpha,
    long sA, long sB, long sC)
{
  const int NT = K >> 5;                       // BK = 32
  __shared__ __bf16 lds[2][4][128][32];        // [buf][Ah|Al|Bh|Bl][row][col]
  const int tid = threadIdx.x;
  const int wid = tid >> 6, lane = tid & 63;
  const int wm = wid >> 1, wn = wid & 1;
  const int row0 = blockIdx.y * 128, col0 = blockIdx.x * 128;
  Ah += (long)blockIdx.z * sA;  Al += (long)blockIdx.z * sA;
  Bh += (long)blockIdx.z * sB;  Bl += (long)blockIdx.z * sB;

  f32x4 acc[4][4];
  const f32x4 zero = {0.f, 0.f, 0.f, 0.f};
  #pragma unroll
  for (int i = 0; i < 4; ++i)
    #pragma unroll
    for (int j = 0; j < 4; ++j) acc[i][j] = zero;

  auto stage = [&](int kt, int buf) {
    long k0 = (long)kt * 32;
    #pragma unroll
    for (int l = 0; l < 2; ++l) {
      int u = l * 256 + tid;
      int r = u >> 2, c4 = u & 3;
      long csrc = (long)((c4 ^ ((r >> 1) & 3)) * 8);
      long ga = (long)(row0 + r) * K + k0 + csrc;
      long gb = (long)(col0 + r) * K + k0 + csrc;
      gload_lds16(Ah + ga, &lds[buf][0][r][c4 * 8]);
      gload_lds16(Al + ga, &lds[buf][1][r][c4 * 8]);
      gload_lds16(Bh + gb, &lds[buf][2][r][c4 * 8]);
      gload_lds16(Bl + gb, &lds[buf][3][r][c4 * 8]);
    }
  };

  stage(0, 0);

  for (int kt = 0; kt < NT; ++kt) {
    const int buf = kt & 1;
    if (kt + 1 < NT) {
      stage(kt + 1, buf ^ 1);
      asm volatile("s_waitcnt vmcnt(8)" ::: "memory");
    } else {
      asm volatile("s_waitcnt vmcnt(0)" ::: "memory");
    }
    asm volatile("s_barrier" ::: "memory");
    bf16x8 ah[4], al[4], bh[4], bl[4];
    #pragma unroll
    for (int mf = 0; mf < 4; ++mf) {
      int r = wm * 64 + mf * 16 + (lane & 15);
      int c4 = (lane >> 4) ^ ((r >> 1) & 3);
      ah[mf] = *(const bf16x8*)&lds[buf][0][r][c4 * 8];
      al[mf] = *(const bf16x8*)&lds[buf][1][r][c4 * 8];
    }
    #pragma unroll
    for (int nf = 0; nf < 4; ++nf) {
      int r = wn * 64 + nf * 16 + (lane & 15);
      int c4 = (lane >> 4) ^ ((r >> 1) & 3);
      bh[nf] = *(const bf16x8*)&lds[buf][2][r][c4 * 8];
      bl[nf] = *(const bf16x8*)&lds[buf][3][r][c4 * 8];
    }
    __builtin_amdgcn_s_setprio(1);
    #pragma unroll
    for (int mf = 0; mf < 4; ++mf)
      #pragma unroll
      for (int nf = 0; nf < 4; ++nf) {
        acc[mf][nf] = __builtin_amdgcn_mfma_f32_16x16x32_bf16(ah[mf], bh[nf], acc[mf][nf], 0, 0, 0);
        acc[mf][nf] = __builtin_amdgcn_mfma_f32_16x16x32_bf16(ah[mf], bl[nf], acc[mf][nf], 0, 0, 0);
        acc[mf][nf] = __builtin_amdgcn_mfma_f32_16x16x32_bf16(al[mf], bh[nf], acc[mf][nf], 0, 0, 0);
      }
    __builtin_amdgcn_s_setprio(0);
    asm volatile("s_barrier" ::: "memory");
  }

  const int crow = (lane >> 4) * 4, ccol = lane & 15;
  #pragma unroll
  for (int mf = 0; mf < 4; ++mf)
    #pragma unroll
    for (int nf = 0; nf < 4; ++nf)
      #pragma unroll
      for (int j = 0; j < 4; ++j) {
        long r = row0 + wm * 64 + mf * 16 + crow + j;
        long c = col0 + wn * 64 + nf * 16 + ccol;
        C[(long)blockIdx.z * sC + r * N + c] = acc[mf][nf][j] * alpha;
      }
}

// ---------------------------------------------------------------------------
// prep_index: grid (512, 4).
// ---------------------------------------------------------------------------
__global__ __launch_bounds__(256) void prep_index(
    const float* __restrict__ x,
    const float* __restrict__ s0, const float* __restrict__ s1,
    const float* __restrict__ s2,
    __bf16* __restrict__ hiB, __bf16* __restrict__ loB, long dstride,
    __bf16* __restrict__ xhi, __bf16* __restrict__ xlo)
{
  __shared__ float tile[64][65];
  int z = blockIdx.y;
  int tid = threadIdx.x;
  if (z < 3) {
    const int R = 2048, Cc = 1024;
    const float* in = (z == 0) ? s0 : (z == 1) ? s1 : s2;
    __bf16* hiT = hiB + (long)z * dstride;
    __bf16* loT = loB + (long)z * dstride;
    int f = blockIdx.x;
    int r0 = (f >> 4) * 64, c0 = (f & 15) * 64;
    #pragma unroll
    for (int j = 0; j < 16; ++j) {
      int idx = tid + j * 256;
      int r = idx >> 6, c = idx & 63;
      tile[r][c] = in[(long)(r0 + r) * Cc + c0 + c];
    }
    __syncthreads();
    #pragma unroll
    for (int j = 0; j < 16; ++j) {
      int idx = tid + j * 256;
      int c = idx >> 6, r = idx & 63;
      float v = tile[r][c];
      __bf16 h = (__bf16)v;
      hiT[(long)(c0 + c) * R + r0 + r] = h;
      loT[(long)(c0 + c) * R + r0 + r] = (__bf16)(v - (float)h);
    }
  } else {
    for (long i = ((long)blockIdx.x * 256 + tid) * 4; i < 8388608; i += 524288) {
      float4 v = *(const float4*)&x[i];
      bf16x4 h, l;
      h[0] = (__bf16)v.x; l[0] = (__bf16)(v.x - (float)h[0]);
      h[1] = (__bf16)v.y; l[1] = (__bf16)(v.y - (float)h[1]);
      h[2] = (__bf16)v.z; l[2] = (__bf16)(v.z - (float)h[2]);
      h[3] = (__bf16)v.w; l[3] = (__bf16)(v.w - (float)h[3]);
      *(bf16x4*)&xhi[i] = h;
      *(bf16x4*)&xlo[i] = l;
    }
  }
}

// ---------------------------------------------------------------------------
// prep_main: grid (512, 7).
// ---------------------------------------------------------------------------
__global__ __launch_bounds__(256) void prep_main(
    const float* __restrict__ s0, const float* __restrict__ s1,
    const float* __restrict__ s2, const float* __restrict__ s3,
    const float* __restrict__ s4, const float* __restrict__ s5,
    const float* __restrict__ wa,
    __bf16* __restrict__ W, long W2, __bf16* __restrict__ owab)
{
  __shared__ float tile[64][65];
  int z = blockIdx.y;
  int tid = threadIdx.x;
  if (z < 6) {
    int R, Cc, r0, c0;
    const float* in;
    if (z < 4) {
      R = 2048; Cc = 1024;
      in = (z == 0) ? s0 : (z == 1) ? s1 : (z == 2) ? s2 : s3;
      r0 = (blockIdx.x >> 4) * 64; c0 = (blockIdx.x & 15) * 64;
    } else {
      R = 1024; Cc = 2048;
      in = (z == 4) ? s4 : s5;
      r0 = (blockIdx.x >> 5) * 64; c0 = (blockIdx.x & 31) * 64;
    }
    __bf16* out = W + (long)z * W2;
    #pragma unroll
    for (int j = 0; j < 16; ++j) {
      int idx = tid + j * 256;
      int r = idx >> 6, c = idx & 63;
      tile[r][c] = in[(long)(r0 + r) * Cc + c0 + c];
    }
    __syncthreads();
    #pragma unroll
    for (int j = 0; j < 16; ++j) {
      int idx = tid + j * 256;
      int c = idx >> 6, r = idx & 63;
      out[(long)(c0 + c) * R + r0 + r] = (__bf16)tile[r][c];
    }
  } else {
    for (long i = ((long)blockIdx.x * 256 + tid) * 4; i < 2097152; i += 524288) {
      float4 v = *(const float4*)&wa[i];
      bf16x4 o;
      o[0] = (__bf16)v.x; o[1] = (__bf16)v.y; o[2] = (__bf16)v.z; o[3] = (__bf16)v.w;
      *(bf16x4*)&owab[i] = o;
    }
  }
}

// ---------------------------------------------------------------------------
// Group softmax over RATIO=4 + weighted sum + fused partial-RoPE on ck.
// ---------------------------------------------------------------------------
__global__ __launch_bounds__(256) void reduce_ckcv(
    const float* __restrict__ base, const float* __restrict__ c_ape,
    const float* __restrict__ cosb, const float* __restrict__ sinb,
    __bf16* __restrict__ ckb, __bf16* __restrict__ cvb)
{
  __shared__ float sck[256];
  const long S = 3072;
  int tid = threadIdx.x;
  int c = blockIdx.x * 256 + tid;
  int g = blockIdx.y, b = blockIdx.z;
  long row0 = (long)b * Tn + 4 * g;
  float lg[4], mx = -1e30f;
  #pragma unroll
  for (int r = 0; r < 4; ++r) {
    lg[r] = base[(row0 + r) * S + 2048 + c] + c_ape[r * 1024 + c];
    mx = fmaxf(mx, lg[r]);
  }
  float ssum = 0.f;
  #pragma unroll
  for (int r = 0; r < 4; ++r) { lg[r] = expf(lg[r] - mx); ssum += lg[r]; }
  float inv = 1.f / ssum, ak = 0.f, av = 0.f;
  #pragma unroll
  for (int r = 0; r < 4; ++r) {
    float w = lg[r] * inv;
    ak = fmaf(base[(row0 + r) * S + c],        w, ak);
    av = fmaf(base[(row0 + r) * S + 1024 + c], w, av);
  }
  long o = ((long)b * Gn + g) * 1024 + c;
  cvb[o] = (__bf16)av;
  sck[tid] = ak;
  __syncthreads();
  int d = c & 127;
  float outk = ak;
  if (d >= 64) {
    int t = 4 * g + 3;
    if (d < 96) {
      int j = d - 64;
      outk = ak * cosb[t * 64 + j] + sck[tid + 32] * sinb[t * 64 + j];
    } else {
      int j = d - 96;
      outk = -sck[tid - 32] * sinb[t * 64 + j] + ak * cosb[t * 64 + j];
    }
  }
  ckb[o] = (__bf16)outk;
}

// ---------------------------------------------------------------------------
// Fused index-path reducer: blocks <1024 do ikeys; blocks >=1024 do iq RMS.
// ---------------------------------------------------------------------------
__global__ __launch_bounds__(1024) void reduce_idx_fused(
    const float* __restrict__ base, const float* __restrict__ i_ape,
    __bf16* __restrict__ khi, __bf16* __restrict__ klo,
    __bf16* __restrict__ qhi, __bf16* __restrict__ qlo)
{
  const long S = 3072;
  int tid = threadIdx.x;
  int bid = blockIdx.x;
  if (bid < Gn * Bn) {
    int g = bid & (Gn - 1), b = bid >> 9;
    long row0 = (long)b * Tn + 4 * g;
    float lg[4], mx = -1e30f;
    #pragma unroll
    for (int r = 0; r < 4; ++r) {
      lg[r] = base[(row0 + r) * S + 1024 + tid] + i_ape[r * 1024 + tid];
      mx = fmaxf(mx, lg[r]);
    }
    float ssum = 0.f;
    #pragma unroll
    for (int r = 0; r < 4; ++r) { lg[r] = expf(lg[r] - mx); ssum += lg[r]; }
    float inv = 1.f / ssum, red = 0.f;
    #pragma unroll
    for (int r = 0; r < 4; ++r) red = fmaf(base[(row0 + r) * S + tid], lg[r] * inv, red);
    float ss = red * red;
    #pragma unroll
    for (int o = 32; o; o >>= 1) ss += __shfl_xor(ss, o);
    float v = red * rsqrtf(ss * (1.f / 64.f) + 1e-6f);
    long oi = ((long)b * Gn + g) * 1024 + tid;
    __bf16 h = (__bf16)v;
    khi[oi] = h; klo[oi] = (__bf16)(v - (float)h);
  } else {
    long row = bid - Gn * Bn;
    float v = base[row * S + 2048 + tid];
    float ss = v * v;
    #pragma unroll
    for (int o = 32; o; o >>= 1) ss += __shfl_xor(ss, o);
    float y = v * rsqrtf(ss * (1.f / 64.f) + 1e-6f);
    __bf16 h = (__bf16)y;
    qhi[row * 1024 + tid] = h;
    qlo[row * 1024 + tid] = (__bf16)(y - (float)h);
  }
}

// ---------------------------------------------------------------------------
// Per-row rms scales from bf16 h.
// ---------------------------------------------------------------------------
__global__ __launch_bounds__(256) void rms_scales(
    const __bf16* __restrict__ h, float* __restrict__ rs)
{
  int wid = threadIdx.x >> 6, lane = threadIdx.x & 63;
  long row = (long)blockIdx.x * 4 + wid;
  const __bf16* hr = h + row * 1024 + lane * 16;
  bf16x8 a = *(const bf16x8*)hr;
  bf16x8 b = *(const bf16x8*)(hr + 8);
  float ss = 0.f;
  #pragma unroll
  for (int j = 0; j < 8; ++j) {
    float x = (float)a[j], y = (float)b[j];
    ss = fmaf(x, x, ss); ss = fmaf(y, y, ss);
  }
  #pragma unroll
  for (int o = 1; o < 64; o <<= 1) ss += __shfl_xor(ss, o);
  if (lane == 0) rs[row] = rsqrtf(ss * (1.f / 1024.f) + 1e-6f);
}

// ---------------------------------------------------------------------------
__global__ __launch_bounds__(256) void topk_kernel(
    const float* __restrict__ iscore, int* __restrict__ selidx, int* __restrict__ selcnt)
{
  int wave = threadIdx.x >> 6, lane = threadIdx.x & 63;
  long bt = (long)blockIdx.x * 4 + wave;
  int t = (int)(bt % Tn);
  const float* row = iscore + bt * Gn;
  int ng = (t + 1) >> 2; if (ng > Gn) ng = Gn;
  int cap = ng < TKn ? ng : TKn;
  float s[8];
  #pragma unroll
  for (int j = 0; j < 8; ++j) {
    int g = lane + 64 * j;
    s[j] = (g < ng) ? row[g] : -INFINITY;
  }
  int* outp = selidx + bt * TKn;
  for (int it = 0; it < cap; ++it) {
    float bv = -INFINITY; int bi = Gn;
    #pragma unroll
    for (int j = 0; j < 8; ++j) {
      int g = lane + 64 * j;
      if (s[j] > bv) { bv = s[j]; bi = g; }
    }
    #pragma unroll
    for (int o = 1; o < 64; o <<= 1) {
      float ov = __shfl_xor(bv, o); int oi = __shfl_xor(bi, o);
      if (ov > bv || (ov == bv && oi < bi)) { bv = ov; bi = oi; }
    }
    if (lane == 0) outp[it] = bi;
    #pragma unroll
    for (int j = 0; j < 8; ++j) if (bi == lane + 64 * j) s[j] = -INFINITY;
  }
  for (int it = cap + lane; it < TKn; it += 64) outp[it] = 0;
  if (lane == 0) selcnt[bt] = cap;
}

// ---------------------------------------------------------------------------
// Gathered sink-softmax attention v8: one wave per (b,t), all 16 heads.
// ---------------------------------------------------------------------------
__global__ __launch_bounds__(256) void attn_kernel(
    const __bf16* __restrict__ q, const __bf16* __restrict__ ckb,
    const __bf16* __restrict__ cvb, const int* __restrict__ selidx,
    const int* __restrict__ selcnt, const float* __restrict__ sink,
    __bf16* __restrict__ out)
{
  __shared__ float sS[4][16][68];
  __shared__ int   sG[4][64];
  const float scale = 0.08838834764831845f;
  int wid = threadIdx.x >> 6, lane = threadIdx.x & 63;
  long bt = (long)blockIdx.x * 4 + wid;
  int b = (int)(bt >> 11);
  int cnt = selcnt[bt];
  int gid = (lane < cnt) ? selidx[bt * TKn + lane] : 0;
  sG[wid][lane] = gid;

  int grp = lane >> 3;
  int sub = lane & 7;
  int h0 = grp * 2, h1 = h0 + 1;
  int d0 = sub * 16;

  const __bf16* qrow = q + bt * 2048;
  float q0[16], q1[16];
  {
    bf16x8 a0 = *(const bf16x8*)&qrow[h0 * 128 + d0];
    bf16x8 a1 = *(const bf16x8*)&qrow[h0 * 128 + d0 + 8];
    bf16x8 c0 = *(const bf16x8*)&qrow[h1 * 128 + d0];
    bf16x8 c1 = *(const bf16x8*)&qrow[h1 * 128 + d0 + 8];
    #pragma unroll
    for (int j = 0; j < 8; ++j) {
      q0[j] = (float)a0[j]; q0[8 + j] = (float)a1[j];
      q1[j] = (float)c0[j]; q1[8 + j] = (float)c1[j];
    }
  }
  __syncthreads();

  for (int i0 = 0; i0 < 64; i0 += 8) {
    #pragma unroll
    for (int u = 0; u < 8; ++u) {
      int i = i0 + u;
      int g = sG[wid][i];
      const __bf16* kr = ckb + ((long)(b * Gn + g)) * 1024 + lane * 16;
      bf16x8 k0 = *(const bf16x8*)kr;
      bf16x8 k1 = *(const bf16x8*)(kr + 8);
      float p0 = 0.f, p1 = 0.f;
      #pragma unroll
      for (int j = 0; j < 8; ++j) {
        float kv = (float)k0[j];
        p0 = fmaf(kv, q0[j], p0); p1 = fmaf(kv, q1[j], p1);
      }
      #pragma unroll
      for (int j = 0; j < 8; ++j) {
        float kv = (float)k1[j];
        p0 = fmaf(kv, q0[8 + j], p0); p1 = fmaf(kv, q1[8 + j], p1);
      }
      p0 += __shfl_xor(p0, 1); p0 += __shfl_xor(p0, 2); p0 += __shfl_xor(p0, 4);
      p1 += __shfl_xor(p1, 1); p1 += __shfl_xor(p1, 2); p1 += __shfl_xor(p1, 4);
      if (sub == 0) { sS[wid][h0][i] = p0; sS[wid][h1][i] = p1; }
    }
  }
  __syncthreads();

  {
    int h = lane >> 2, qtr = lane & 3;
    float sv[16];
    float mx = -INFINITY;
    #pragma unroll
    for (int j = 0; j < 16; ++j) {
      int i = qtr * 16 + j;
      float s = (i < cnt) ? sS[wid][h][i] * scale : -INFINITY;
      sv[j] = s; mx = fmaxf(mx, s);
    }
    mx = fmaxf(mx, __shfl_xor(mx, 1));
    mx = fmaxf(mx, __shfl_xor(mx, 2));
    float snk = sink[h];
    mx = fmaxf(mx, snk);
    float sum = 0.f;
    #pragma unroll
    for (int j = 0; j < 16; ++j) { sv[j] = __expf(sv[j] - mx); sum += sv[j]; }
    sum += __shfl_xor(sum, 1);
    sum += __shfl_xor(sum, 2);
    sum += __expf(snk - mx);
    float inv = 1.f / sum;
    #pragma unroll
    for (int j = 0; j < 16; ++j) sS[wid][h][qtr * 16 + j] = sv[j] * inv;
  }
  __syncthreads();

  float o0[16], o1[16];
  #pragma unroll
  for (int j = 0; j < 16; ++j) { o0[j] = 0.f; o1[j] = 0.f; }
  for (int i0 = 0; i0 < 64; i0 += 8) {
    #pragma unroll
    for (int u = 0; u < 8; ++u) {
      int i = i0 + u;
      int g = sG[wid][i];
      float p0 = sS[wid][h0][i], p1 = sS[wid][h1][i];
      const __bf16* vr = cvb + ((long)(b * Gn + g)) * 1024 + lane * 16;
      bf16x8 v0 = *(const bf16x8*)vr;
      bf16x8 v1 = *(const bf16x8*)(vr + 8);
      #pragma unroll
      for (int j = 0; j < 8; ++j) {
        float vv = (float)v0[j];
        o0[j] = fmaf(p0, vv, o0[j]); o1[j] = fmaf(p1, vv, o1[j]);
      }
      #pragma unroll
      for (int j = 0; j < 8; ++j) {
        float vv = (float)v1[j];
        o0[8 + j] = fmaf(p0, vv, o0[8 + j]); o1[8 + j] = fmaf(p1, vv, o1[8 + j]);
      }
    }
  }
  __bf16* ob = out + bt * 2048;
  bf16x8 w;
  #pragma unroll
  for (int j = 0; j < 8; ++j) w[j] = (__bf16)o0[j];
  *(bf16x8*)&ob[h0 * 128 + d0] = w;
  #pragma unroll
  for (int j = 0; j < 8; ++j) w[j] = (__bf16)o0[8 + j];
  *(bf16x8*)&ob[h0 * 128 + d0 + 8] = w;
  #pragma unroll
  for (int j = 0; j < 8; ++j) w[j] = (__bf16)o1[j];
  *(bf16x8*)&ob[h1 * 128 + d0] = w;
  #pragma unroll
  for (int j = 0; j < 8; ++j) w[j] = (__bf16)o1[8 + j];
  *(bf16x8*)&ob[h1 * 128 + d0 + 8] = w;
}

// ---------------------------------------------------------------------------
extern "C" void kernel_launch(void* const* d_in, const int* in_sizes, int n_in,
                              void* d_out, int out_size, void* d_ws, size_t ws_size,
                              hipStream_t stream) {
  const float* x     = (const float*)d_in[0];
  const float* cosb  = (const float*)d_in[1];
  const float* sinb  = (const float*)d_in[2];
  const float* q_a_w = (const float*)d_in[3];
  const float* q_b_w = (const float*)d_in[4];
  const float* ck_w  = (const float*)d_in[5];
  const float* cv_w  = (const float*)d_in[6];
  const float* cg_w  = (const float*)d_in[7];
  const float* c_ape = (const float*)d_in[8];
  const float* iq_w  = (const float*)d_in[9];
  const float* ik_w  = (const float*)d_in[10];
  const float* ig_w  = (const float*)d_in[11];
  const float* i_ape = (const float*)d_in[12];
  const float* sink  = (const float*)d_in[13];
  const float* o_wa  = (const float*)d_in[14];
  const float* o_pb  = (const float*)d_in[15];
  float* outp = (float*)d_out;
  float* ws = (float*)d_ws;

  const long F  = 4194304;
  const long M1 = 1048576;

  float* b_all = ws;
  float*  iscore = ws + F;
  __bf16* oatt_b = (__bf16*)(ws + F);
  __bf16* hb_b   = (__bf16*)ws;            // bf16 h (out-proj output)

  // d_out overlays (time-disjoint, stream-serialized):
  __bf16* iq_hi = (__bf16*)d_out;
  __bf16* iq_lo = (__bf16*)d_out + 4194304;
  __bf16* qb    = (__bf16*)d_out;          // bf16 q (after selection phase)

  char* tp = (char*)(ws + 3 * F);
  __bf16* ckb = (__bf16*)tp;     tp += (size_t)M1 * 4;
  __bf16* cvb = (__bf16*)tp;     tp += (size_t)M1 * 4;
  int*   selidx = (int*)tp;      tp += 2097152;
  int*   selcnt = selidx + Bn * Tn * TKn;
  __bf16* ikeys_hi = (__bf16*)tp; tp += 2097152;
  __bf16* ikeys_lo = (__bf16*)tp; tp += 2097152;
  __bf16* xhi = (__bf16*)tp;      tp += 16777216;
  __bf16* xlo = (__bf16*)tp;      tp += 16777216;
  __bf16* W   = (__bf16*)tp;      tp += 7 * 4194304;
  __bf16* qa_buf = (__bf16*)tp;   tp += 8388608;
  float*  rs     = (float*)tp;    tp += 16384;          // 4096 f32 scales
  const long W2 = 2097152;
  __bf16* Whi = W;            __bf16* Wlo = W + 3 * W2;
  __bf16* ckT  = W;           // ck|cv|cg|qa contiguous (phase-2 overlay)
  __bf16* qbT  = W + 4*W2;
  __bf16* opbT = W + 5*W2;   __bf16* owab = W + 6*W2;

  // ---- merged conversions: index path ----
  prep_index<<<dim3(512, 4), 256, 0, stream>>>(
      x, ik_w, ig_w, iq_w, Whi, Wlo, W2, xhi, xlo);

  // ---- index path: split GEMM (R24: 256x192 flat kt-body, 2 barriers/kt) ----
  gemm_split_flat<<<dim3(16, 16), 512, 0, stream>>>(xhi, xlo, Whi, Wlo, b_all,
      4096, 3072, 2048, 1.f);
  reduce_idx_fused<<<dim3(Gn * Bn + Bn * Tn), 1024, 0, stream>>>(
      b_all, i_ape, ikeys_hi, ikeys_lo, iq_hi, iq_lo);

  // ---- selection (R19 pipelined split GEMM) ----
  gemm_split<<<dim3(4, 16, 2), 256, 0, stream>>>(iq_hi, iq_lo, ikeys_hi, ikeys_lo, iscore,
      2048, 512, 1024, 1.f / 128.f, (long)2048 * 1024, (long)512 * 1024, (long)2048 * 512);
  topk_kernel<<<dim3(Bn * Tn / 4), 256, 0, stream>>>(iscore, selidx, selcnt);

  // ---- merged conversions: main-path weights ----
  prep_main<<<dim3(512, 7), 256, 0, stream>>>(
      ck_w, cv_w, cg_w, q_a_w, q_b_w, o_pb, o_wa, W, W2, owab);

  // ---- merged kv+qa GEMM (R20: 256x256 8-phase, grid 256 = 1/CU) ----
  gemm_kvqa_8ph<<<dim3(16, 16), 512, 0, stream>>>(xhi, ckT, b_all, qa_buf);
  reduce_ckcv<<<dim3(4, Gn, Bn), 256, 0, stream>>>(b_all, c_ape, cosb, sinb, ckb, cvb);

  // ---- q GEMM (pipelined, fused rope epilogue) -> bf16 q (d_out) ----
  gemm_pipe<1><<<dim3(16, 32), 256, 0, stream>>>(
      qa_buf, qbT, qb, 2048, 1024, cosb, sinb, nullptr);

  // ---- attention v8 (bf16 q) ----
  attn_kernel<<<dim3(Bn * Tn / 4), 256, 0, stream>>>(qb, ckb, cvb, selidx, selcnt, sink, oatt_b);

  // ---- output projection (pipelined, bf16 h direct) ----
  gemm_pipe<0><<<dim3(8, 32), 256, 0, stream>>>(
      oatt_b, owab, hb_b, 1024, 2048, nullptr, nullptr, nullptr);
  rms_scales<<<dim3(1024), 256, 0, stream>>>(hb_b, rs);
  // ---- final GEMM (pipelined, fused rms row scales) ----
  gemm_pipe<2><<<dim3(16, 32), 256, 0, stream>>>(
      hb_b, opbT, outp, 2048, 1024, nullptr, nullptr, rs);
}

// Round 7
// 493.546 us; speedup vs baseline: 1.0869x; 1.0294x over previous
//
#include <hip/hip_runtime.h>
#include <hip/hip_bf16.h>
#include <math.h>

constexpr int Bn  = 2;
constexpr int Tn  = 2048;
constexpr int NHn = 16;
constexpr int NKVn= 8;
constexpr int Gn  = 512;
constexpr int TKn = 64;

typedef __attribute__((ext_vector_type(8))) __bf16 bf16x8;
typedef __attribute__((ext_vector_type(4))) __bf16 bf16x4;
typedef __attribute__((ext_vector_type(2))) __bf16 bf16x2;
typedef __attribute__((ext_vector_type(4))) float f32x4;

__device__ __forceinline__ void gload_lds16(const void* g, void* l) {
  __builtin_amdgcn_global_load_lds(
      (const __attribute__((address_space(1))) unsigned int*)g,
      (__attribute__((address_space(3))) unsigned int*)l, 16, 0, 0);
}

// ---------------------------------------------------------------------------
// gemm_kvqa_8ph (R20): 256x256 tile, 8 waves, BK=64 (2 sub-phases of 32),
// 4 phases per K-tile with counted vmcnt(4) (never 0 in steady state),
// double-buffered 128 KiB LDS, proven c4^((r>>1)&3) swizzle (0 conflicts).
// ---------------------------------------------------------------------------
__global__ __launch_bounds__(512) void gemm_kvqa_8ph(
    const __bf16* __restrict__ A, const __bf16* __restrict__ Bt,
    float* __restrict__ Cf, __bf16* __restrict__ Cq)
{
  constexpr int K = 2048;
  constexpr int NT = K / 64;                  // 32 K-tiles
  __shared__ __bf16 lds[2][2][2][256][32];    // [buf][op A/B][ph][row][col] = 128 KiB
  const int tid = threadIdx.x;
  const int wid = tid >> 6, lane = tid & 63;
  const int wm = wid >> 2, wn = wid & 3;      // 2 (M) x 4 (N) wave grid
  const int row0 = blockIdx.y * 256, col0 = blockIdx.x * 256;

  f32x4 acc[8][4];
  const f32x4 zero = {0.f, 0.f, 0.f, 0.f};
  #pragma unroll
  for (int i = 0; i < 8; ++i)
    #pragma unroll
    for (int j = 0; j < 4; ++j) acc[i][j] = zero;

  // stage one (op, ph) half-tile (256 rows x 32 cols) of K-tile kt into buf
  auto stage1 = [&](int kt, int op, int ph, int buf) {
    long k0 = (long)kt * 64 + ph * 32;
    const __bf16* src = op ? Bt : A;
    const int base0 = op ? col0 : row0;
    #pragma unroll
    for (int l = 0; l < 2; ++l) {
      int u = l * 512 + tid;
      int r = u >> 2, c4 = u & 3;
      long csrc = (long)((c4 ^ ((r >> 1) & 3)) * 8);
      gload_lds16(src + (long)(base0 + r) * K + k0 + csrc, &lds[buf][op][ph][r][c4 * 8]);
    }
  };

  // prologue: stage kt0 halves H0..H3 = (A,0),(B,0),(A,1),(B,1)
  stage1(0, 0, 0, 0);
  stage1(0, 1, 0, 0);
  stage1(0, 0, 1, 0);
  stage1(0, 1, 1, 0);
  asm volatile("s_waitcnt vmcnt(4)" ::: "memory");   // H0,H1 done; H2,H3 in flight
  asm volatile("s_barrier" ::: "memory");

  for (int kt = 0; kt < NT; ++kt) {
    const int buf = kt & 1;
    const bool pre = (kt + 1 < NT);
    bf16x8 afA[4], afB[4], bf[4];

    // ---- P0: ph0, acc rows mf0-3 ----
    #pragma unroll
    for (int i = 0; i < 4; ++i) {
      int r = wm * 128 + i * 16 + (lane & 15);
      int c4 = (lane >> 4) ^ ((r >> 1) & 3);
      afA[i] = *(const bf16x8*)&lds[buf][0][0][r][c4 * 8];
    }
    #pragma unroll
    for (int i = 0; i < 4; ++i) {
      int r = wn * 64 + i * 16 + (lane & 15);
      int c4 = (lane >> 4) ^ ((r >> 1) & 3);
      bf[i] = *(const bf16x8*)&lds[buf][1][0][r][c4 * 8];
    }
    if (pre) stage1(kt + 1, 0, 0, buf ^ 1);
    asm volatile("s_barrier" ::: "memory");
    asm volatile("s_waitcnt lgkmcnt(0)" ::: "memory");
    __builtin_amdgcn_sched_barrier(0);
    __builtin_amdgcn_s_setprio(1);
    #pragma unroll
    for (int i = 0; i < 4; ++i)
      #pragma unroll
      for (int j = 0; j < 4; ++j)
        acc[i][j] = __builtin_amdgcn_mfma_f32_16x16x32_bf16(afA[i], bf[j], acc[i][j], 0, 0, 0);
    __builtin_amdgcn_s_setprio(0);
    asm volatile("s_barrier" ::: "memory");

    // ---- P1: ph0, acc rows mf4-7 ----
    #pragma unroll
    for (int i = 0; i < 4; ++i) {
      int r = wm * 128 + (i + 4) * 16 + (lane & 15);
      int c4 = (lane >> 4) ^ ((r >> 1) & 3);
      afB[i] = *(const bf16x8*)&lds[buf][0][0][r][c4 * 8];
    }
    if (pre) {
      stage1(kt + 1, 1, 0, buf ^ 1);
      asm volatile("s_waitcnt vmcnt(4)" ::: "memory");  // confirm kt.H2,H3
    } else {
      asm volatile("s_waitcnt vmcnt(0)" ::: "memory");
    }
    asm volatile("s_barrier" ::: "memory");
    asm volatile("s_waitcnt lgkmcnt(0)" ::: "memory");
    __builtin_amdgcn_sched_barrier(0);
    __builtin_amdgcn_s_setprio(1);
    #pragma unroll
    for (int i = 0; i < 4; ++i)
      #pragma unroll
      for (int j = 0; j < 4; ++j)
        acc[i + 4][j] = __builtin_amdgcn_mfma_f32_16x16x32_bf16(afB[i], bf[j], acc[i + 4][j], 0, 0, 0);
    __builtin_amdgcn_s_setprio(0);
    asm volatile("s_barrier" ::: "memory");

    // ---- P2: ph1, acc rows mf0-3 ----
    #pragma unroll
    for (int i = 0; i < 4; ++i) {
      int r = wm * 128 + i * 16 + (lane & 15);
      int c4 = (lane >> 4) ^ ((r >> 1) & 3);
      afA[i] = *(const bf16x8*)&lds[buf][0][1][r][c4 * 8];
    }
    #pragma unroll
    for (int i = 0; i < 4; ++i) {
      int r = wn * 64 + i * 16 + (lane & 15);
      int c4 = (lane >> 4) ^ ((r >> 1) & 3);
      bf[i] = *(const bf16x8*)&lds[buf][1][1][r][c4 * 8];
    }
    if (pre) stage1(kt + 1, 0, 1, buf ^ 1);
    asm volatile("s_barrier" ::: "memory");
    asm volatile("s_waitcnt lgkmcnt(0)" ::: "memory");
    __builtin_amdgcn_sched_barrier(0);
    __builtin_amdgcn_s_setprio(1);
    #pragma unroll
    for (int i = 0; i < 4; ++i)
      #pragma unroll
      for (int j = 0; j < 4; ++j)
        acc[i][j] = __builtin_amdgcn_mfma_f32_16x16x32_bf16(afA[i], bf[j], acc[i][j], 0, 0, 0);
    __builtin_amdgcn_s_setprio(0);
    asm volatile("s_barrier" ::: "memory");

    // ---- P3: ph1, acc rows mf4-7 ----
    #pragma unroll
    for (int i = 0; i < 4; ++i) {
      int r = wm * 128 + (i + 4) * 16 + (lane & 15);
      int c4 = (lane >> 4) ^ ((r >> 1) & 3);
      afB[i] = *(const bf16x8*)&lds[buf][0][1][r][c4 * 8];
    }
    if (pre) {
      stage1(kt + 1, 1, 1, buf ^ 1);
      asm volatile("s_waitcnt vmcnt(4)" ::: "memory");  // confirm kt+1.H0,H1
    }
    asm volatile("s_barrier" ::: "memory");
    asm volatile("s_waitcnt lgkmcnt(0)" ::: "memory");
    __builtin_amdgcn_sched_barrier(0);
    __builtin_amdgcn_s_setprio(1);
    #pragma unroll
    for (int i = 0; i < 4; ++i)
      #pragma unroll
      for (int j = 0; j < 4; ++j)
        acc[i + 4][j] = __builtin_amdgcn_mfma_f32_16x16x32_bf16(afB[i], bf[j], acc[i + 4][j], 0, 0, 0);
    __builtin_amdgcn_s_setprio(0);
    asm volatile("s_barrier" ::: "memory");
  }

  const int crow = (lane >> 4) * 4, ccol = lane & 15;
  const bool isQ = (col0 >= 3072);
  #pragma unroll
  for (int mf = 0; mf < 8; ++mf)
    #pragma unroll
    for (int nf = 0; nf < 4; ++nf)
      #pragma unroll
      for (int j = 0; j < 4; ++j) {
        long r = row0 + wm * 128 + mf * 16 + crow + j;
        long c = col0 + wn * 64 + nf * 16 + ccol;
        float v = acc[mf][nf][j];
        if (isQ) Cq[r * 1024 + (c - 3072)] = (__bf16)v;
        else     Cf[r * 3072 + c] = v;
      }
}

// ---------------------------------------------------------------------------
// gemm_split_8ph (R21, validated 139.4 us): 3-product split GEMM, 256x192
// tile (grid 16x16 = 256 blocks = 1/CU), 8 waves (2Mx4N), per-wave 128x48,
// acc[8][3], BK=32. LDS [Ah|Al|Bh+Bl] dbuf = 112 KiB.
// Phases: P0 hh(r0-3,12 MFMA) P1 hl+lh(r0-3,24) P2 hh(r4-7,12)
// P3 hl+lh(r4-7,24). Counted vmcnt: pieces SB(3) SAh(2) SAl(2) issued in
// that order for kt+1; P3 waits vmcnt(2), P0 vmcnt(3).
// Per-acc product order hh->hl->lh per K-slice == R19 (bit-identical).
// ---------------------------------------------------------------------------
__global__ __launch_bounds__(512) void gemm_split_8ph(
    const __bf16* __restrict__ Ah, const __bf16* __restrict__ Al,
    const __bf16* __restrict__ Bh, const __bf16* __restrict__ Bl,
    float* __restrict__ C, int M, int N, int K, float alpha)
{
  const int NT = K >> 5;                      // BK = 32
  constexpr int LA_H = 0;                     // 256*32
  constexpr int LA_L = 8192;
  constexpr int LB_H = 16384;                 // 192*32 = 6144
  constexpr int LBUF = 28672;                 // elems per buffer
  __shared__ __bf16 sm[2 * LBUF];             // 114688 B
  const int tid = threadIdx.x;
  const int wid = tid >> 6, lane = tid & 63;
  const int wm = wid >> 2, wn = wid & 3;      // 2 (M) x 4 (N)
  const int row0 = blockIdx.y * 256, col0 = blockIdx.x * 192;

  f32x4 acc[8][3];
  const f32x4 zero = {0.f, 0.f, 0.f, 0.f};
  #pragma unroll
  for (int i = 0; i < 8; ++i)
    #pragma unroll
    for (int j = 0; j < 3; ++j) acc[i][j] = zero;

  // A half-tile (256x32) of stream which (0=hi,1=lo): 2 loads/thread
  auto stageA = [&](int kt, int buf, int which) {
    long k0 = (long)kt * 32;
    const __bf16* src = which ? Al : Ah;
    __bf16* dst = &sm[buf * LBUF + (which ? LA_L : LA_H)];
    #pragma unroll
    for (int l = 0; l < 2; ++l) {
      int u = l * 512 + tid;
      int r = u >> 2, c4 = u & 3;
      long csrc = (long)((c4 ^ ((r >> 1) & 3)) * 8);
      gload_lds16(src + (long)(row0 + r) * K + k0 + csrc, dst + u * 8);
    }
  };
  // B combined half-tile (Bh 192x32 then Bl 192x32): 3 loads/thread
  auto stageB = [&](int kt, int buf) {
    long k0 = (long)kt * 32;
    __bf16* dst = &sm[buf * LBUF + LB_H];
    #pragma unroll
    for (int l = 0; l < 3; ++l) {
      int u = l * 512 + tid;
      int v = (u < 768) ? u : u - 768;
      const __bf16* src = (u < 768) ? Bh : Bl;
      int r = v >> 2, c4 = v & 3;
      long csrc = (long)((c4 ^ ((r >> 1) & 3)) * 8);
      gload_lds16(src + (long)(col0 + r) * K + k0 + csrc, dst + u * 8);
    }
  };

  // prologue: SB(0), SAh(0), SAl(0); confirm SB+SAh, leave SAl in flight
  stageB(0, 0);
  stageA(0, 0, 0);
  stageA(0, 0, 1);
  asm volatile("s_waitcnt vmcnt(2)" ::: "memory");
  asm volatile("s_barrier" ::: "memory");

  for (int kt = 0; kt < NT; ++kt) {
    const int buf = kt & 1;
    const bool pre = (kt + 1 < NT);
    bf16x8 a_h[4], a_l[4], b_h[3], b_l[3];

    // ---- P0: rows mf0-3, hh ----
    #pragma unroll
    for (int i = 0; i < 4; ++i) {
      int r = wm * 128 + i * 16 + (lane & 15);
      int c4 = (lane >> 4) ^ ((r >> 1) & 3);
      a_h[i] = *(const bf16x8*)&sm[buf * LBUF + LA_H + r * 32 + c4 * 8];
    }
    #pragma unroll
    for (int j = 0; j < 3; ++j) {
      int r = wn * 48 + j * 16 + (lane & 15);
      int c4 = (lane >> 4) ^ ((r >> 1) & 3);
      b_h[j] = *(const bf16x8*)&sm[buf * LBUF + LB_H + r * 32 + c4 * 8];
    }
    if (pre) {
      stageB(kt + 1, buf ^ 1);
      asm volatile("s_waitcnt vmcnt(3)" ::: "memory");  // drain SAl(kt), keep SB(kt+1)
    } else {
      asm volatile("s_waitcnt vmcnt(0)" ::: "memory");
    }
    asm volatile("s_barrier" ::: "memory");
    asm volatile("s_waitcnt lgkmcnt(0)" ::: "memory");
    __builtin_amdgcn_sched_barrier(0);
    __builtin_amdgcn_s_setprio(1);
    #pragma unroll
    for (int i = 0; i < 4; ++i)
      #pragma unroll
      for (int j = 0; j < 3; ++j)
        acc[i][j] = __builtin_amdgcn_mfma_f32_16x16x32_bf16(a_h[i], b_h[j], acc[i][j], 0, 0, 0);
    __builtin_amdgcn_s_setprio(0);
    asm volatile("s_barrier" ::: "memory");

    // ---- P1: rows mf0-3, hl + lh ----
    #pragma unroll
    for (int i = 0; i < 4; ++i) {
      int r = wm * 128 + i * 16 + (lane & 15);
      int c4 = (lane >> 4) ^ ((r >> 1) & 3);
      a_l[i] = *(const bf16x8*)&sm[buf * LBUF + LA_L + r * 32 + c4 * 8];
    }
    #pragma unroll
    for (int j = 0; j < 3; ++j) {
      int r = wn * 48 + j * 16 + (lane & 15);
      int c4 = (lane >> 4) ^ ((r >> 1) & 3);
      b_l[j] = *(const bf16x8*)&sm[buf * LBUF + LB_H + 6144 + r * 32 + c4 * 8];
    }
    if (pre) stageA(kt + 1, buf ^ 1, 0);
    asm volatile("s_barrier" ::: "memory");
    asm volatile("s_waitcnt lgkmcnt(0)" ::: "memory");
    __builtin_amdgcn_sched_barrier(0);
    __builtin_amdgcn_s_setprio(1);
    #pragma unroll
    for (int i = 0; i < 4; ++i)
      #pragma unroll
      for (int j = 0; j < 3; ++j) {
        acc[i][j] = __builtin_amdgcn_mfma_f32_16x16x32_bf16(a_h[i], b_l[j], acc[i][j], 0, 0, 0);
        acc[i][j] = __builtin_amdgcn_mfma_f32_16x16x32_bf16(a_l[i], b_h[j], acc[i][j], 0, 0, 0);
      }
    __builtin_amdgcn_s_setprio(0);
    asm volatile("s_barrier" ::: "memory");

    // ---- P2: rows mf4-7, hh ----
    #pragma unroll
    for (int i = 0; i < 4; ++i) {
      int r = wm * 128 + (i + 4) * 16 + (lane & 15);
      int c4 = (lane >> 4) ^ ((r >> 1) & 3);
      a_h[i] = *(const bf16x8*)&sm[buf * LBUF + LA_H + r * 32 + c4 * 8];
    }
    if (pre) stageA(kt + 1, buf ^ 1, 1);
    asm volatile("s_barrier" ::: "memory");
    asm volatile("s_waitcnt lgkmcnt(0)" ::: "memory");
    __builtin_amdgcn_sched_barrier(0);
    __builtin_amdgcn_s_setprio(1);
    #pragma unroll
    for (int i = 0; i < 4; ++i)
      #pragma unroll
      for (int j = 0; j < 3; ++j)
        acc[i + 4][j] = __builtin_amdgcn_mfma_f32_16x16x32_bf16(a_h[i], b_h[j], acc[i + 4][j], 0, 0, 0);
    __builtin_amdgcn_s_setprio(0);
    asm volatile("s_barrier" ::: "memory");

    // ---- P3: rows mf4-7, hl + lh ----
    #pragma unroll
    for (int i = 0; i < 4; ++i) {
      int r = wm * 128 + (i + 4) * 16 + (lane & 15);
      int c4 = (lane >> 4) ^ ((r >> 1) & 3);
      a_l[i] = *(const bf16x8*)&sm[buf * LBUF + LA_L + r * 32 + c4 * 8];
    }
    if (pre)
      asm volatile("s_waitcnt vmcnt(2)" ::: "memory");  // drain SB+SAh(kt+1), keep SAl(kt+1)
    asm volatile("s_barrier" ::: "memory");
    asm volatile("s_waitcnt lgkmcnt(0)" ::: "memory");
    __builtin_amdgcn_sched_barrier(0);
    __builtin_amdgcn_s_setprio(1);
    #pragma unroll
    for (int i = 0; i < 4; ++i)
      #pragma unroll
      for (int j = 0; j < 3; ++j) {
        acc[i + 4][j] = __builtin_amdgcn_mfma_f32_16x16x32_bf16(a_h[i], b_l[j], acc[i + 4][j], 0, 0, 0);
        acc[i + 4][j] = __builtin_amdgcn_mfma_f32_16x16x32_bf16(a_l[i], b_h[j], acc[i + 4][j], 0, 0, 0);
      }
    __builtin_amdgcn_s_setprio(0);
    asm volatile("s_barrier" ::: "memory");
  }

  const int crow = (lane >> 4) * 4, ccol = lane & 15;
  #pragma unroll
  for (int mf = 0; mf < 8; ++mf)
    #pragma unroll
    for (int nf = 0; nf < 3; ++nf)
      #pragma unroll
      for (int j = 0; j < 4; ++j) {
        long r = row0 + wm * 128 + mf * 16 + crow + j;
        long c = col0 + wn * 48 + nf * 16 + ccol;
        C[r * N + c] = acc[mf][nf][j] * alpha;
      }
}

// ---------------------------------------------------------------------------
// gemm_split_sel (R25): selection GEMM, 64x64 tile, grid (8,32,2) = 512
// blocks = 2/CU (old 128-block launch left half the GPU idle). 4 waves
// (2Mx2N, 32x32/wave, acc[2][2]), BK=32, R19 schedule: stage(kt+1) ->
// vmcnt(4) -> barrier -> frag reads -> 12 MFMA -> barrier.
// Per-acc product order hh->hl->lh per K-slice == R19 (bit-identical).
// ---------------------------------------------------------------------------
__global__ __launch_bounds__(256) void gemm_split_sel(
    const __bf16* __restrict__ Ah, const __bf16* __restrict__ Al,
    const __bf16* __restrict__ Bh, const __bf16* __restrict__ Bl,
    float* __restrict__ C, int M, int N, int K, float alpha,
    long sA, long sB, long sC)
{
  const int NT = K >> 5;                       // BK = 32
  __shared__ __bf16 lds[2][4][64][32];         // [buf][Ah|Al|Bh|Bl][row][col] = 32 KiB
  const int tid = threadIdx.x;
  const int wid = tid >> 6, lane = tid & 63;
  const int wm = wid >> 1, wn = wid & 1;
  const int row0 = blockIdx.y * 64, col0 = blockIdx.x * 64;
  Ah += (long)blockIdx.z * sA;  Al += (long)blockIdx.z * sA;
  Bh += (long)blockIdx.z * sB;  Bl += (long)blockIdx.z * sB;

  f32x4 acc[2][2];
  const f32x4 zero = {0.f, 0.f, 0.f, 0.f};
  #pragma unroll
  for (int i = 0; i < 2; ++i)
    #pragma unroll
    for (int j = 0; j < 2; ++j) acc[i][j] = zero;

  auto stage = [&](int kt, int buf) {
    long k0 = (long)kt * 32;
    int u = tid;
    int r = u >> 2, c4 = u & 3;                // 64 rows x 4 groups
    long csrc = (long)((c4 ^ ((r >> 1) & 3)) * 8);
    long ga = (long)(row0 + r) * K + k0 + csrc;
    long gb = (long)(col0 + r) * K + k0 + csrc;
    gload_lds16(Ah + ga, &lds[buf][0][r][c4 * 8]);
    gload_lds16(Al + ga, &lds[buf][1][r][c4 * 8]);
    gload_lds16(Bh + gb, &lds[buf][2][r][c4 * 8]);
    gload_lds16(Bl + gb, &lds[buf][3][r][c4 * 8]);
  };

  stage(0, 0);

  for (int kt = 0; kt < NT; ++kt) {
    const int buf = kt & 1;
    if (kt + 1 < NT) {
      stage(kt + 1, buf ^ 1);
      asm volatile("s_waitcnt vmcnt(4)" ::: "memory");
    } else {
      asm volatile("s_waitcnt vmcnt(0)" ::: "memory");
    }
    asm volatile("s_barrier" ::: "memory");
    bf16x8 ah[2], al[2], bh[2], bl[2];
    #pragma unroll
    for (int mf = 0; mf < 2; ++mf) {
      int r = wm * 32 + mf * 16 + (lane & 15);
      int c4 = (lane >> 4) ^ ((r >> 1) & 3);
      ah[mf] = *(const bf16x8*)&lds[buf][0][r][c4 * 8];
      al[mf] = *(const bf16x8*)&lds[buf][1][r][c4 * 8];
    }
    #pragma unroll
    for (int nf = 0; nf < 2; ++nf) {
      int r = wn * 32 + nf * 16 + (lane & 15);
      int c4 = (lane >> 4) ^ ((r >> 1) & 3);
      bh[nf] = *(const bf16x8*)&lds[buf][2][r][c4 * 8];
      bl[nf] = *(const bf16x8*)&lds[buf][3][r][c4 * 8];
    }
    __builtin_amdgcn_s_setprio(1);
    #pragma unroll
    for (int mf = 0; mf < 2; ++mf)
      #pragma unroll
      for (int nf = 0; nf < 2; ++nf) {
        acc[mf][nf] = __builtin_amdgcn_mfma_f32_16x16x32_bf16(ah[mf], bh[nf], acc[mf][nf], 0, 0, 0);
        acc[mf][nf] = __builtin_amdgcn_mfma_f32_16x16x32_bf16(ah[mf], bl[nf], acc[mf][nf], 0, 0, 0);
        acc[mf][nf] = __builtin_amdgcn_mfma_f32_16x16x32_bf16(al[mf], bh[nf], acc[mf][nf], 0, 0, 0);
      }
    __builtin_amdgcn_s_setprio(0);
    asm volatile("s_barrier" ::: "memory");
  }

  const int crow = (lane >> 4) * 4, ccol = lane & 15;
  #pragma unroll
  for (int mf = 0; mf < 2; ++mf)
    #pragma unroll
    for (int nf = 0; nf < 2; ++nf)
      #pragma unroll
      for (int j = 0; j < 4; ++j) {
        long r = row0 + wm * 32 + mf * 16 + crow + j;
        long c = col0 + wn * 32 + nf * 16 + ccol;
        C[(long)blockIdx.z * sC + r * N + c] = acc[mf][nf][j] * alpha;
      }
}

// ---------------------------------------------------------------------------
// Unified pipelined GEMM (R13 schedule, runtime K): C = A @ Bt^T.
// EPI 0: bf16 out.  EPI 1: rope bf16 q layout (N=2048).  EPI 2: f32 * rs[r].
// ---------------------------------------------------------------------------
template<int EPI>
__global__ __launch_bounds__(256) void gemm_pipe(
    const __bf16* __restrict__ A, const __bf16* __restrict__ Bt,
    void* __restrict__ Cp, int N, int K,
    const float* __restrict__ cosb, const float* __restrict__ sinb,
    const float* __restrict__ rs)
{
  const int NT = K >> 6;
  __shared__ __bf16 lds[2][2][2][128][32];
  const int tid = threadIdx.x;
  const int wid = tid >> 6, lane = tid & 63;
  const int wm = wid >> 1, wn = wid & 1;
  const int row0 = blockIdx.y * 128, col0 = blockIdx.x * 128;

  f32x4 acc[4][4];
  const f32x4 zero = {0.f, 0.f, 0.f, 0.f};
  #pragma unroll
  for (int i = 0; i < 4; ++i)
    #pragma unroll
    for (int j = 0; j < 4; ++j) acc[i][j] = zero;

  auto stage = [&](int kt, int p, int buf) {
    long k0 = (long)kt * 64 + p * 32;
    #pragma unroll
    for (int l = 0; l < 2; ++l) {
      int u = l * 256 + tid;
      int r = u >> 2, c4 = u & 3;
      long csrc = (long)((c4 ^ ((r >> 1) & 3)) * 8);
      gload_lds16(A  + (long)(row0 + r) * K + k0 + csrc, &lds[buf][0][p][r][c4 * 8]);
      gload_lds16(Bt + (long)(col0 + r) * K + k0 + csrc, &lds[buf][1][p][r][c4 * 8]);
    }
  };

  stage(0, 0, 0);
  stage(0, 1, 0);

  for (int kt = 0; kt < NT; ++kt) {
    const int buf = kt & 1;
    #pragma unroll
    for (int ph = 0; ph < 2; ++ph) {
      if (kt + 1 < NT) {
        stage(kt + 1, ph, buf ^ 1);
        asm volatile("s_waitcnt vmcnt(8)" ::: "memory");
      } else {
        if (ph == 0) asm volatile("s_waitcnt vmcnt(4)" ::: "memory");
        else         asm volatile("s_waitcnt vmcnt(0)" ::: "memory");
      }
      asm volatile("s_barrier" ::: "memory");
      bf16x8 af[4], bfr[4];
      #pragma unroll
      for (int mf = 0; mf < 4; ++mf) {
        int r = wm * 64 + mf * 16 + (lane & 15);
        int c4 = (lane >> 4) ^ ((r >> 1) & 3);
        af[mf] = *(const bf16x8*)&lds[buf][0][ph][r][c4 * 8];
      }
      #pragma unroll
      for (int nf = 0; nf < 4; ++nf) {
        int r = wn * 64 + nf * 16 + (lane & 15);
        int c4 = (lane >> 4) ^ ((r >> 1) & 3);
        bfr[nf] = *(const bf16x8*)&lds[buf][1][ph][r][c4 * 8];
      }
      __builtin_amdgcn_s_setprio(1);
      #pragma unroll
      for (int mf = 0; mf < 4; ++mf)
        #pragma unroll
        for (int nf = 0; nf < 4; ++nf)
          acc[mf][nf] = __builtin_amdgcn_mfma_f32_16x16x32_bf16(af[mf], bfr[nf], acc[mf][nf], 0, 0, 0);
      __builtin_amdgcn_s_setprio(0);
      asm volatile("s_barrier" ::: "memory");
    }
  }

  const int crow = (lane >> 4) * 4, ccol = lane & 15;
  if constexpr (EPI == 1) {
    __bf16* C = (__bf16*)Cp;
    if (wn == 1) {
      #pragma unroll
      for (int mf = 0; mf < 4; ++mf)
        #pragma unroll
        for (int j = 0; j < 4; ++j) {
          long r = row0 + wm * 64 + mf * 16 + crow + j;
          int t = (int)(r & 2047);
          #pragma unroll
          for (int nfp = 0; nfp < 2; ++nfp) {
            int jj = nfp * 16 + ccol;
            float c = cosb[t * 64 + jj], s = sinb[t * 64 + jj];
            float x1 = acc[mf][nfp][j];
            float x2 = acc[mf][nfp + 2][j];
            C[r * N + col0 + 64 + jj] = (__bf16)(x1 * c + x2 * s);
            C[r * N + col0 + 96 + jj] = (__bf16)(-x1 * s + x2 * c);
          }
        }
    } else {
      #pragma unroll
      for (int mf = 0; mf < 4; ++mf)
        #pragma unroll
        for (int nf = 0; nf < 4; ++nf)
          #pragma unroll
          for (int j = 0; j < 4; ++j) {
            long r = row0 + wm * 64 + mf * 16 + crow + j;
            long c = col0 + nf * 16 + ccol;
            C[r * N + c] = (__bf16)acc[mf][nf][j];
          }
    }
  } else {
    #pragma unroll
    for (int mf = 0; mf < 4; ++mf)
      #pragma unroll
      for (int nf = 0; nf < 4; ++nf)
        #pragma unroll
        for (int j = 0; j < 4; ++j) {
          long r = row0 + wm * 64 + mf * 16 + crow + j;
          long c = col0 + wn * 64 + nf * 16 + ccol;
          float v = acc[mf][nf][j];
          if constexpr (EPI == 2)
            ((float*)Cp)[r * N + c] = v * rs[r];
          else
            ((__bf16*)Cp)[r * N + c] = (__bf16)v;
        }
  }
}

// ---------------------------------------------------------------------------
// prep_index: grid (512, 4). R25: vectorized bf16x8 transpose-stores.
// ---------------------------------------------------------------------------
__global__ __launch_bounds__(256) void prep_index(
    const float* __restrict__ x,
    const float* __restrict__ s0, const float* __restrict__ s1,
    const float* __restrict__ s2,
    __bf16* __restrict__ hiB, __bf16* __restrict__ loB, long dstride,
    __bf16* __restrict__ xhi, __bf16* __restrict__ xlo)
{
  __shared__ float tile[64][65];
  int z = blockIdx.y;
  int tid = threadIdx.x;
  if (z < 3) {
    const int R = 2048, Cc = 1024;
    const float* in = (z == 0) ? s0 : (z == 1) ? s1 : s2;
    __bf16* hiT = hiB + (long)z * dstride;
    __bf16* loT = loB + (long)z * dstride;
    int f = blockIdx.x;
    int r0 = (f >> 4) * 64, c0 = (f & 15) * 64;
    #pragma unroll
    for (int j = 0; j < 16; ++j) {
      int idx = tid + j * 256;
      int r = idx >> 6, c = idx & 63;
      tile[r][c] = in[(long)(r0 + r) * Cc + c0 + c];
    }
    __syncthreads();
    #pragma unroll
    for (int j = 0; j < 2; ++j) {
      int idx = tid + j * 256;
      int c = idx >> 3, r = (idx & 7) * 8;
      bf16x8 h8, l8;
      #pragma unroll
      for (int i = 0; i < 8; ++i) {
        float v = tile[r + i][c];
        __bf16 h = (__bf16)v;
        h8[i] = h; l8[i] = (__bf16)(v - (float)h);
      }
      *(bf16x8*)&hiT[(long)(c0 + c) * R + r0 + r] = h8;
      *(bf16x8*)&loT[(long)(c0 + c) * R + r0 + r] = l8;
    }
  } else {
    for (long i = ((long)blockIdx.x * 256 + tid) * 4; i < 8388608; i += 524288) {
      float4 v = *(const float4*)&x[i];
      bf16x4 h, l;
      h[0] = (__bf16)v.x; l[0] = (__bf16)(v.x - (float)h[0]);
      h[1] = (__bf16)v.y; l[1] = (__bf16)(v.y - (float)h[1]);
      h[2] = (__bf16)v.z; l[2] = (__bf16)(v.z - (float)h[2]);
      h[3] = (__bf16)v.w; l[3] = (__bf16)(v.w - (float)h[3]);
      *(bf16x4*)&xhi[i] = h;
      *(bf16x4*)&xlo[i] = l;
    }
  }
}

// ---------------------------------------------------------------------------
// prep_main: grid (512, 7). R25: vectorized bf16x8 transpose-stores.
// ---------------------------------------------------------------------------
__global__ __launch_bounds__(256) void prep_main(
    const float* __restrict__ s0, const float* __restrict__ s1,
    const float* __restrict__ s2, const float* __restrict__ s3,
    const float* __restrict__ s4, const float* __restrict__ s5,
    const float* __restrict__ wa,
    __bf16* __restrict__ W, long W2, __bf16* __restrict__ owab)
{
  __shared__ float tile[64][65];
  int z = blockIdx.y;
  int tid = threadIdx.x;
  if (z < 6) {
    int R, Cc, r0, c0;
    const float* in;
    if (z < 4) {
      R = 2048; Cc = 1024;
      in = (z == 0) ? s0 : (z == 1) ? s1 : (z == 2) ? s2 : s3;
      r0 = (blockIdx.x >> 4) * 64; c0 = (blockIdx.x & 15) * 64;
    } else {
      R = 1024; Cc = 2048;
      in = (z == 4) ? s4 : s5;
      r0 = (blockIdx.x >> 5) * 64; c0 = (blockIdx.x & 31) * 64;
    }
    __bf16* out = W + (long)z * W2;
    #pragma unroll
    for (int j = 0; j < 16; ++j) {
      int idx = tid + j * 256;
      int r = idx >> 6, c = idx & 63;
      tile[r][c] = in[(long)(r0 + r) * Cc + c0 + c];
    }
    __syncthreads();
    #pragma unroll
    for (int j = 0; j < 2; ++j) {
      int idx = tid + j * 256;
      int c = idx >> 3, r = (idx & 7) * 8;
      bf16x8 o8;
      #pragma unroll
      for (int i = 0; i < 8; ++i) o8[i] = (__bf16)tile[r + i][c];
      *(bf16x8*)&out[(long)(c0 + c) * R + r0 + r] = o8;
    }
  } else {
    for (long i = ((long)blockIdx.x * 256 + tid) * 4; i < 2097152; i += 524288) {
      float4 v = *(const float4*)&wa[i];
      bf16x4 o;
      o[0] = (__bf16)v.x; o[1] = (__bf16)v.y; o[2] = (__bf16)v.z; o[3] = (__bf16)v.w;
      *(bf16x4*)&owab[i] = o;
    }
  }
}

// ---------------------------------------------------------------------------
// Group softmax over RATIO=4 + weighted sum + fused partial-RoPE on ck.
// ---------------------------------------------------------------------------
__global__ __launch_bounds__(256) void reduce_ckcv(
    const float* __restrict__ base, const float* __restrict__ c_ape,
    const float* __restrict__ cosb, const float* __restrict__ sinb,
    __bf16* __restrict__ ckb, __bf16* __restrict__ cvb)
{
  __shared__ float sck[256];
  const long S = 3072;
  int tid = threadIdx.x;
  int c = blockIdx.x * 256 + tid;
  int g = blockIdx.y, b = blockIdx.z;
  long row0 = (long)b * Tn + 4 * g;
  float lg[4], mx = -1e30f;
  #pragma unroll
  for (int r = 0; r < 4; ++r) {
    lg[r] = base[(row0 + r) * S + 2048 + c] + c_ape[r * 1024 + c];
    mx = fmaxf(mx, lg[r]);
  }
  float ssum = 0.f;
  #pragma unroll
  for (int r = 0; r < 4; ++r) { lg[r] = expf(lg[r] - mx); ssum += lg[r]; }
  float inv = 1.f / ssum, ak = 0.f, av = 0.f;
  #pragma unroll
  for (int r = 0; r < 4; ++r) {
    float w = lg[r] * inv;
    ak = fmaf(base[(row0 + r) * S + c],        w, ak);
    av = fmaf(base[(row0 + r) * S + 1024 + c], w, av);
  }
  long o = ((long)b * Gn + g) * 1024 + c;
  cvb[o] = (__bf16)av;
  sck[tid] = ak;
  __syncthreads();
  int d = c & 127;
  float outk = ak;
  if (d >= 64) {
    int t = 4 * g + 3;
    if (d < 96) {
      int j = d - 64;
      outk = ak * cosb[t * 64 + j] + sck[tid + 32] * sinb[t * 64 + j];
    } else {
      int j = d - 96;
      outk = -sck[tid - 32] * sinb[t * 64 + j] + ak * cosb[t * 64 + j];
    }
  }
  ckb[o] = (__bf16)outk;
}

// ---------------------------------------------------------------------------
// Fused index-path reducer: blocks <1024 do ikeys; blocks >=1024 do iq RMS.
// ---------------------------------------------------------------------------
__global__ __launch_bounds__(1024) void reduce_idx_fused(
    const float* __restrict__ base, const float* __restrict__ i_ape,
    __bf16* __restrict__ khi, __bf16* __restrict__ klo,
    __bf16* __restrict__ qhi, __bf16* __restrict__ qlo)
{
  const long S = 3072;
  int tid = threadIdx.x;
  int bid = blockIdx.x;
  if (bid < Gn * Bn) {
    int g = bid & (Gn - 1), b = bid >> 9;
    long row0 = (long)b * Tn + 4 * g;
    float lg[4], mx = -1e30f;
    #pragma unroll
    for (int r = 0; r < 4; ++r) {
      lg[r] = base[(row0 + r) * S + 1024 + tid] + i_ape[r * 1024 + tid];
      mx = fmaxf(mx, lg[r]);
    }
    float ssum = 0.f;
    #pragma unroll
    for (int r = 0; r < 4; ++r) { lg[r] = expf(lg[r] - mx); ssum += lg[r]; }
    float inv = 1.f / ssum, red = 0.f;
    #pragma unroll
    for (int r = 0; r < 4; ++r) red = fmaf(base[(row0 + r) * S + tid], lg[r] * inv, red);
    float ss = red * red;
    #pragma unroll
    for (int o = 32; o; o >>= 1) ss += __shfl_xor(ss, o);
    float v = red * rsqrtf(ss * (1.f / 64.f) + 1e-6f);
    long oi = ((long)b * Gn + g) * 1024 + tid;
    __bf16 h = (__bf16)v;
    khi[oi] = h; klo[oi] = (__bf16)(v - (float)h);
  } else {
    long row = bid - Gn * Bn;
    float v = base[row * S + 2048 + tid];
    float ss = v * v;
    #pragma unroll
    for (int o = 32; o; o >>= 1) ss += __shfl_xor(ss, o);
    float y = v * rsqrtf(ss * (1.f / 64.f) + 1e-6f);
    __bf16 h = (__bf16)y;
    qhi[row * 1024 + tid] = h;
    qlo[row * 1024 + tid] = (__bf16)(y - (float)h);
  }
}

// ---------------------------------------------------------------------------
// Per-row rms scales from bf16 h.
// ---------------------------------------------------------------------------
__global__ __launch_bounds__(256) void rms_scales(
    const __bf16* __restrict__ h, float* __restrict__ rs)
{
  int wid = threadIdx.x >> 6, lane = threadIdx.x & 63;
  long row = (long)blockIdx.x * 4 + wid;
  const __bf16* hr = h + row * 1024 + lane * 16;
  bf16x8 a = *(const bf16x8*)hr;
  bf16x8 b = *(const bf16x8*)(hr + 8);
  float ss = 0.f;
  #pragma unroll
  for (int j = 0; j < 8; ++j) {
    float x = (float)a[j], y = (float)b[j];
    ss = fmaf(x, x, ss); ss = fmaf(y, y, ss);
  }
  #pragma unroll
  for (int o = 1; o < 64; o <<= 1) ss += __shfl_xor(ss, o);
  if (lane == 0) rs[row] = rsqrtf(ss * (1.f / 1024.f) + 1e-6f);
}

// ---------------------------------------------------------------------------
__global__ __launch_bounds__(256) void topk_kernel(
    const float* __restrict__ iscore, int* __restrict__ selidx, int* __restrict__ selcnt)
{
  int wave = threadIdx.x >> 6, lane = threadIdx.x & 63;
  long bt = (long)blockIdx.x * 4 + wave;
  int t = (int)(bt % Tn);
  const float* row = iscore + bt * Gn;
  int ng = (t + 1) >> 2; if (ng > Gn) ng = Gn;
  int cap = ng < TKn ? ng : TKn;
  float s[8];
  #pragma unroll
  for (int j = 0; j < 8; ++j) {
    int g = lane + 64 * j;
    s[j] = (g < ng) ? row[g] : -INFINITY;
  }
  int* outp = selidx + bt * TKn;
  for (int it = 0; it < cap; ++it) {
    float bv = -INFINITY; int bi = Gn;
    #pragma unroll
    for (int j = 0; j < 8; ++j) {
      int g = lane + 64 * j;
      if (s[j] > bv) { bv = s[j]; bi = g; }
    }
    #pragma unroll
    for (int o = 1; o < 64; o <<= 1) {
      float ov = __shfl_xor(bv, o); int oi = __shfl_xor(bi, o);
      if (ov > bv || (ov == bv && oi < bi)) { bv = ov; bi = oi; }
    }
    if (lane == 0) outp[it] = bi;
    #pragma unroll
    for (int j = 0; j < 8; ++j) if (bi == lane + 64 * j) s[j] = -INFINITY;
  }
  for (int it = cap + lane; it < TKn; it += 64) outp[it] = 0;
  if (lane == 0) selcnt[bt] = cap;
}

// ---------------------------------------------------------------------------
// Gathered sink-softmax attention v8: one wave per (b,t), all 16 heads.
// ---------------------------------------------------------------------------
__global__ __launch_bounds__(256) void attn_kernel(
    const __bf16* __restrict__ q, const __bf16* __restrict__ ckb,
    const __bf16* __restrict__ cvb, const int* __restrict__ selidx,
    const int* __restrict__ selcnt, const float* __restrict__ sink,
    __bf16* __restrict__ out)
{
  __shared__ float sS[4][16][68];
  __shared__ int   sG[4][64];
  const float scale = 0.08838834764831845f;
  int wid = threadIdx.x >> 6, lane = threadIdx.x & 63;
  long bt = (long)blockIdx.x * 4 + wid;
  int b = (int)(bt >> 11);
  int cnt = selcnt[bt];
  int gid = (lane < cnt) ? selidx[bt * TKn + lane] : 0;
  sG[wid][lane] = gid;

  int grp = lane >> 3;
  int sub = lane & 7;
  int h0 = grp * 2, h1 = h0 + 1;
  int d0 = sub * 16;

  const __bf16* qrow = q + bt * 2048;
  float q0[16], q1[16];
  {
    bf16x8 a0 = *(const bf16x8*)&qrow[h0 * 128 + d0];
    bf16x8 a1 = *(const bf16x8*)&qrow[h0 * 128 + d0 + 8];
    bf16x8 c0 = *(const bf16x8*)&qrow[h1 * 128 + d0];
    bf16x8 c1 = *(const bf16x8*)&qrow[h1 * 128 + d0 + 8];
    #pragma unroll
    for (int j = 0; j < 8; ++j) {
      q0[j] = (float)a0[j]; q0[8 + j] = (float)a1[j];
      q1[j] = (float)c0[j]; q1[8 + j] = (float)c1[j];
    }
  }
  __syncthreads();

  for (int i0 = 0; i0 < 64; i0 += 8) {
    #pragma unroll
    for (int u = 0; u < 8; ++u) {
      int i = i0 + u;
      int g = sG[wid][i];
      const __bf16* kr = ckb + ((long)(b * Gn + g)) * 1024 + lane * 16;
      bf16x8 k0 = *(const bf16x8*)kr;
      bf16x8 k1 = *(const bf16x8*)(kr + 8);
      float p0 = 0.f, p1 = 0.f;
      #pragma unroll
      for (int j = 0; j < 8; ++j) {
        float kv = (float)k0[j];
        p0 = fmaf(kv, q0[j], p0); p1 = fmaf(kv, q1[j], p1);
      }
      #pragma unroll
      for (int j = 0; j < 8; ++j) {
        float kv = (float)k1[j];
        p0 = fmaf(kv, q0[8 + j], p0); p1 = fmaf(kv, q1[8 + j], p1);
      }
      p0 += __shfl_xor(p0, 1); p0 += __shfl_xor(p0, 2); p0 += __shfl_xor(p0, 4);
      p1 += __shfl_xor(p1, 1); p1 += __shfl_xor(p1, 2); p1 += __shfl_xor(p1, 4);
      if (sub == 0) { sS[wid][h0][i] = p0; sS[wid][h1][i] = p1; }
    }
  }
  __syncthreads();

  {
    int h = lane >> 2, qtr = lane & 3;
    float sv[16];
    float mx = -INFINITY;
    #pragma unroll
    for (int j = 0; j < 16; ++j) {
      int i = qtr * 16 + j;
      float s = (i < cnt) ? sS[wid][h][i] * scale : -INFINITY;
      sv[j] = s; mx = fmaxf(mx, s);
    }
    mx = fmaxf(mx, __shfl_xor(mx, 1));
    mx = fmaxf(mx, __shfl_xor(mx, 2));
    float snk = sink[h];
    mx = fmaxf(mx, snk);
    float sum = 0.f;
    #pragma unroll
    for (int j = 0; j < 16; ++j) { sv[j] = __expf(sv[j] - mx); sum += sv[j]; }
    sum += __shfl_xor(sum, 1);
    sum += __shfl_xor(sum, 2);
    sum += __expf(snk - mx);
    float inv = 1.f / sum;
    #pragma unroll
    for (int j = 0; j < 16; ++j) sS[wid][h][qtr * 16 + j] = sv[j] * inv;
  }
  __syncthreads();

  float o0[16], o1[16];
  #pragma unroll
  for (int j = 0; j < 16; ++j) { o0[j] = 0.f; o1[j] = 0.f; }
  for (int i0 = 0; i0 < 64; i0 += 8) {
    #pragma unroll
    for (int u = 0; u < 8; ++u) {
      int i = i0 + u;
      int g = sG[wid][i];
      float p0 = sS[wid][h0][i], p1 = sS[wid][h1][i];
      const __bf16* vr = cvb + ((long)(b * Gn + g)) * 1024 + lane * 16;
      bf16x8 v0 = *(const bf16x8*)vr;
      bf16x8 v1 = *(const bf16x8*)(vr + 8);
      #pragma unroll
      for (int j = 0; j < 8; ++j) {
        float vv = (float)v0[j];
        o0[j] = fmaf(p0, vv, o0[j]); o1[j] = fmaf(p1, vv, o1[j]);
      }
      #pragma unroll
      for (int j = 0; j < 8; ++j) {
        float vv = (float)v1[j];
        o0[8 + j] = fmaf(p0, vv, o0[8 + j]); o1[8 + j] = fmaf(p1, vv, o1[8 + j]);
      }
    }
  }
  __bf16* ob = out + bt * 2048;
  bf16x8 w;
  #pragma unroll
  for (int j = 0; j < 8; ++j) w[j] = (__bf16)o0[j];
  *(bf16x8*)&ob[h0 * 128 + d0] = w;
  #pragma unroll
  for (int j = 0; j < 8; ++j) w[j] = (__bf16)o0[8 + j];
  *(bf16x8*)&ob[h0 * 128 + d0 + 8] = w;
  #pragma unroll
  for (int j = 0; j < 8; ++j) w[j] = (__bf16)o1[j];
  *(bf16x8*)&ob[h1 * 128 + d0] = w;
  #pragma unroll
  for (int j = 0; j < 8; ++j) w[j] = (__bf16)o1[8 + j];
  *(bf16x8*)&ob[h1 * 128 + d0 + 8] = w;
}

// ---------------------------------------------------------------------------
extern "C" void kernel_launch(void* const* d_in, const int* in_sizes, int n_in,
                              void* d_out, int out_size, void* d_ws, size_t ws_size,
                              hipStream_t stream) {
  const float* x     = (const float*)d_in[0];
  const float* cosb  = (const float*)d_in[1];
  const float* sinb  = (const float*)d_in[2];
  const float* q_a_w = (const float*)d_in[3];
  const float* q_b_w = (const float*)d_in[4];
  const float* ck_w  = (const float*)d_in[5];
  const float* cv_w  = (const float*)d_in[6];
  const float* cg_w  = (const float*)d_in[7];
  const float* c_ape = (const float*)d_in[8];
  const float* iq_w  = (const float*)d_in[9];
  const float* ik_w  = (const float*)d_in[10];
  const float* ig_w  = (const float*)d_in[11];
  const float* i_ape = (const float*)d_in[12];
  const float* sink  = (const float*)d_in[13];
  const float* o_wa  = (const float*)d_in[14];
  const float* o_pb  = (const float*)d_in[15];
  float* outp = (float*)d_out;
  float* ws = (float*)d_ws;

  const long F  = 4194304;
  const long M1 = 1048576;

  float* b_all = ws;
  float*  iscore = ws + F;
  __bf16* oatt_b = (__bf16*)(ws + F);
  __bf16* hb_b   = (__bf16*)ws;            // bf16 h (out-proj output)

  // d_out overlays (time-disjoint, stream-serialized):
  __bf16* iq_hi = (__bf16*)d_out;
  __bf16* iq_lo = (__bf16*)d_out + 4194304;
  __bf16* qb    = (__bf16*)d_out;          // bf16 q (after selection phase)

  char* tp = (char*)(ws + 3 * F);
  __bf16* ckb = (__bf16*)tp;     tp += (size_t)M1 * 4;
  __bf16* cvb = (__bf16*)tp;     tp += (size_t)M1 * 4;
  int*   selidx = (int*)tp;      tp += 2097152;
  int*   selcnt = selidx + Bn * Tn * TKn;
  __bf16* ikeys_hi = (__bf16*)tp; tp += 2097152;
  __bf16* ikeys_lo = (__bf16*)tp; tp += 2097152;
  __bf16* xhi = (__bf16*)tp;      tp += 16777216;
  __bf16* xlo = (__bf16*)tp;      tp += 16777216;
  __bf16* W   = (__bf16*)tp;      tp += 7 * 4194304;
  __bf16* qa_buf = (__bf16*)tp;   tp += 8388608;
  float*  rs     = (float*)tp;    tp += 16384;          // 4096 f32 scales
  const long W2 = 2097152;
  __bf16* Whi = W;            __bf16* Wlo = W + 3 * W2;
  __bf16* ckT  = W;           // ck|cv|cg|qa contiguous (phase-2 overlay)
  __bf16* qbT  = W + 4*W2;
  __bf16* opbT = W + 5*W2;   __bf16* owab = W + 6*W2;

  // ---- merged conversions: index path ----
  prep_index<<<dim3(512, 4), 256, 0, stream>>>(
      x, ik_w, ig_w, iq_w, Whi, Wlo, W2, xhi, xlo);

  // ---- index path: split GEMM (R21: 256x192 4-phase, grid 256 = 1/CU) ----
  gemm_split_8ph<<<dim3(16, 16), 512, 0, stream>>>(xhi, xlo, Whi, Wlo, b_all,
      4096, 3072, 2048, 1.f);
  reduce_idx_fused<<<dim3(Gn * Bn + Bn * Tn), 1024, 0, stream>>>(
      b_all, i_ape, ikeys_hi, ikeys_lo, iq_hi, iq_lo);

  // ---- selection (R25: 64x64 tile, 512 blocks = 2/CU) ----
  gemm_split_sel<<<dim3(8, 32, 2), 256, 0, stream>>>(iq_hi, iq_lo, ikeys_hi, ikeys_lo, iscore,
      2048, 512, 1024, 1.f / 128.f, (long)2048 * 1024, (long)512 * 1024, (long)2048 * 512);
  topk_kernel<<<dim3(Bn * Tn / 4), 256, 0, stream>>>(iscore, selidx, selcnt);

  // ---- merged conversions: main-path weights ----
  prep_main<<<dim3(512, 7), 256, 0, stream>>>(
      ck_w, cv_w, cg_w, q_a_w, q_b_w, o_pb, o_wa, W, W2, owab);

  // ---- merged kv+qa GEMM (R20: 256x256 8-phase, grid 256 = 1/CU) ----
  gemm_kvqa_8ph<<<dim3(16, 16), 512, 0, stream>>>(xhi, ckT, b_all, qa_buf);
  reduce_ckcv<<<dim3(4, Gn, Bn), 256, 0, stream>>>(b_all, c_ape, cosb, sinb, ckb, cvb);

  // ---- q GEMM (pipelined, fused rope epilogue) -> bf16 q (d_out) ----
  gemm_pipe<1><<<dim3(16, 32), 256, 0, stream>>>(
      qa_buf, qbT, qb, 2048, 1024, cosb, sinb, nullptr);

  // ---- attention v8 (bf16 q) ----
  attn_kernel<<<dim3(Bn * Tn / 4), 256, 0, stream>>>(qb, ckb, cvb, selidx, selcnt, sink, oatt_b);

  // ---- output projection (pipelined, bf16 h direct) ----
  gemm_pipe<0><<<dim3(8, 32), 256, 0, stream>>>(
      oatt_b, owab, hb_b, 1024, 2048, nullptr, nullptr, nullptr);
  rms_scales<<<dim3(1024), 256, 0, stream>>>(hb_b, rs);
  // ---- final GEMM (pipelined, fused rms row scales) ----
  gemm_pipe<2><<<dim3(16, 32), 256, 0, stream>>>(
      hb_b, opbT, outp, 2048, 1024, nullptr, nullptr, rs);
}